// Round 9
// baseline (607.360 us; speedup 1.0000x reference)
//
#include <hip/hip_runtime.h>
#include <hip/hip_fp16.h>

// VectorQuantize forward, round 8:
// - flashS: swapped-operand QK (S^T = mfma(E, z)) -> lane owns ONE row n.
//   u loads 4x float4 (was 16 scalars), P stores 4x 8B (was 16x 2B),
//   row-stats (lsum + top-2) fused lane-locally; per-block stats to fixed
//   slots (deterministic). rowpass + cvtzf + ZF buffer eliminated.
// - rowfin: merge 32 candidates/row + fixed-order lsum + exact fp32 argmax.
// - pvS: pv2 with flash4-style gload_lds dbuf for P (ONE barrier/iter) and
//   ET B-frags direct from global (L2-resident) -> es LDS (64KB) deleted.
// - inproj32, zqred, outproj2, finalize, prep kernels unchanged.

#define NROWS 8192
#define KCL   8192
#define DDIM  256
#define CIN   1024
#define TSEQ  2048
#define EPSL  1e-10f
#define MHAT  (-140.0f)

#define OUT_SC   (4*CIN*TSEQ)   // 8388608 == 4 * NROWS * DDIM (split-K parts fit)

// ---- old-path (round-1 fallback) ws offsets ----
#define ZD_OFF   0
#define ZQ_OFF   (NROWS*DDIM)
#define E2_OFF   (2*NROWS*DDIM)
#define CS_OFF   (E2_OFF + KCL)
#define CNT_OFF  (CS_OFF + KCL)
#define VQ_OFF   (CNT_OFF + KCL)
#define LINV_OFF (VQ_OFF + 4)

// ---- new-path ws offsets (float words) ----
#define ZD2W   0
#define ZQ2W   2097152
#define EBW    4194304
#define ETW    5242880
#define WOBW   6291456
#define ZDBW   6422528          // bf16 zd [N][D] (4MB; replaces ZF)
#define E2W    7471104
#define C2W    7479296
#define LINVW  7487488
#define CSUMW  7495680
#define CNTW   7503872
#define VQW    7512064
#define PW     7512128
#define ENDW   (PW + 33554432)
// transient stats live in the zq region (consumed by rowfin before zqred
// overwrites with zq): lsumpart[16][8192], candv[32][8192], candi[32][8192]
#define LSPW   ZQ2W
#define CVW    (ZQ2W + 131072)
#define CIW    (ZQ2W + 393216)

using short8v = __attribute__((ext_vector_type(8))) short;
using short4v = __attribute__((ext_vector_type(4))) short;
using f32x16  = __attribute__((ext_vector_type(16))) float;

__device__ __forceinline__ ushort f2bf(float f) {
  unsigned int x = __float_as_uint(f);
  return (ushort)((x + 0x7FFFu + ((x >> 16) & 1u)) >> 16);
}
__device__ __forceinline__ float bf2f(ushort h) {
  return __uint_as_float(((unsigned int)h) << 16);
}
__device__ __forceinline__ short8v pack8(float4 a, float4 b) {
  short8v v;
  v[0] = (short)f2bf(a.x); v[1] = (short)f2bf(a.y);
  v[2] = (short)f2bf(a.z); v[3] = (short)f2bf(a.w);
  v[4] = (short)f2bf(b.x); v[5] = (short)f2bf(b.y);
  v[6] = (short)f2bf(b.z); v[7] = (short)f2bf(b.w);
  return v;
}
__device__ __forceinline__ void gload16(const void* g, void* l) {
  __builtin_amdgcn_global_load_lds(
      (const __attribute__((address_space(1))) unsigned int*)g,
      (__attribute__((address_space(3))) unsigned int*)l, 16, 0, 0);
}

// ================= shared prep =================

__global__ __launch_bounds__(256) void e2_kernel(const float* __restrict__ E,
                                                 float* __restrict__ e2) {
  const int tid = threadIdx.x;
  const int k = blockIdx.x * 64 + (tid >> 2);
  const int p = tid & 3;
  const float* row = E + (size_t)k * DDIM + p * 64;
  float s = 0.f;
#pragma unroll
  for (int j = 0; j < 16; ++j) {
    const float4 v = *reinterpret_cast<const float4*>(row + j * 4);
    s += v.x * v.x + v.y * v.y + v.z * v.z + v.w * v.w;
  }
  s += __shfl_xor(s, 1);
  s += __shfl_xor(s, 2);
  if (p == 0) e2[k] = s;
}

__global__ __launch_bounds__(256) void e2c2_kernel(const float* __restrict__ E,
                                                   float* __restrict__ e2,
                                                   float* __restrict__ c2) {
  const int tid = threadIdx.x;
  const int k = blockIdx.x * 64 + (tid >> 2);
  const int p = tid & 3;
  const float* row = E + (size_t)k * DDIM + p * 64;
  float s = 0.f;
#pragma unroll
  for (int j = 0; j < 16; ++j) {
    const float4 v = *reinterpret_cast<const float4*>(row + j * 4);
    s += v.x * v.x + v.y * v.y + v.z * v.z + v.w * v.w;
  }
  s += __shfl_xor(s, 1);
  s += __shfl_xor(s, 2);
  if (p == 0) { e2[k] = s; c2[k] = -s - MHAT; }
}

// generic f32 -> bf16 cast (used for Wo and for zd -> ZDB)
__global__ __launch_bounds__(256) void cvtwob_kernel(const float* __restrict__ W,
                                                     ushort* __restrict__ Wb) {
  const size_t i = ((size_t)blockIdx.x * 256 + threadIdx.x) * 8;
  const float4 a = *reinterpret_cast<const float4*>(W + i);
  const float4 b = *reinterpret_cast<const float4*>(W + i + 4);
  *reinterpret_cast<short8v*>(Wb + i) = pack8(a, b);
}

// E [K][D] f32 -> ET [D][K] bf16 AND EB [K][D] bf16 (fused)
__global__ __launch_bounds__(256) void etprep_kernel(const float* __restrict__ E,
                                                     ushort* __restrict__ ET,
                                                     ushort* __restrict__ EB) {
  __shared__ float tb[64 * 68];
  const int t = threadIdx.x;
  const int kb = (blockIdx.x & 127) * 64;
  const int db = (blockIdx.x >> 7) * 64;
#pragma unroll
  for (int it = 0; it < 4; ++it) {
    const int r = (t >> 4) + it * 16;
    const int c = (t & 15) * 4;
    const float4 v = *reinterpret_cast<const float4*>(E + (size_t)(kb + r) * DDIM + db + c);
    tb[r * 68 + c] = v.x; tb[r * 68 + c + 1] = v.y;
    tb[r * 68 + c + 2] = v.z; tb[r * 68 + c + 3] = v.w;
    short4v o;
    o[0] = (short)f2bf(v.x); o[1] = (short)f2bf(v.y);
    o[2] = (short)f2bf(v.z); o[3] = (short)f2bf(v.w);
    *reinterpret_cast<short4v*>(EB + (size_t)(kb + r) * DDIM + db + c) = o;
  }
  __syncthreads();
  const int dl = t >> 2, kg = (t & 3) * 16;
  short8v o0, o1;
#pragma unroll
  for (int j = 0; j < 8; ++j) o0[j] = (short)f2bf(tb[(kg + j) * 68 + dl]);
#pragma unroll
  for (int j = 0; j < 8; ++j) o1[j] = (short)f2bf(tb[(kg + 8 + j) * 68 + dl]);
  ushort* dst = ET + (size_t)(db + dl) * KCL + kb + kg;
  *reinterpret_cast<short8v*>(dst) = o0;
  *reinterpret_cast<short8v*>(dst + 8) = o1;
}

// ================= inproj32 (fp32, 32-row blocks, CIN split 2) =================
__global__ __launch_bounds__(256) void inproj32_kernel(const float* __restrict__ z,
                                                       const float* __restrict__ Wi,
                                                       const float* __restrict__ bi,
                                                       float* __restrict__ zd) {
  __shared__ float wi_s[32 * 260];
  __shared__ float zc[32 * 32];
  const int tid = threadIdx.x;
  const int nb = blockIdx.x >> 1, cih = blockIdx.x & 1;
  const int n0 = nb * 32;
  const int b = n0 / TSEQ;
  const int t0 = n0 % TSEQ;
  const float* zb = z + (size_t)b * CIN * TSEQ;
  const int ibase = cih * 512;

  const int dg = tid & 63;
  const int d0 = dg * 4;
  const int wv = tid >> 6;
  const int r0 = wv * 8;

  float acc[4][8];
#pragma unroll
  for (int c = 0; c < 4; ++c)
#pragma unroll
    for (int r = 0; r < 8; ++r) acc[c][r] = 0.f;

  for (int i0 = ibase; i0 < ibase + 512; i0 += 32) {
    __syncthreads();
    {
      const int iiq = (tid & 7) * 4;
      const int dt = tid >> 3;
#pragma unroll
      for (int p = 0; p < 8; ++p) {
        const int d = dt + p * 32;
        const float4 w = *reinterpret_cast<const float4*>(Wi + (size_t)d * CIN + i0 + iiq);
        wi_s[(iiq + 0) * 260 + d] = w.x;
        wi_s[(iiq + 1) * 260 + d] = w.y;
        wi_s[(iiq + 2) * 260 + d] = w.z;
        wi_s[(iiq + 3) * 260 + d] = w.w;
      }
      const int rr = tid & 31;
      const int iib = tid >> 5;
#pragma unroll
      for (int p = 0; p < 4; ++p) {
        const int ii = iib + p * 8;
        zc[ii * 32 + rr] = zb[(size_t)(i0 + ii) * TSEQ + t0 + rr];
      }
    }
    __syncthreads();
#pragma unroll
    for (int ii = 0; ii < 32; ++ii) {
      const float4 w = *reinterpret_cast<const float4*>(&wi_s[ii * 260 + d0]);
#pragma unroll
      for (int rq = 0; rq < 2; ++rq) {
        const float4 zv = *reinterpret_cast<const float4*>(&zc[ii * 32 + r0 + rq * 4]);
        const float zz[4] = {zv.x, zv.y, zv.z, zv.w};
#pragma unroll
        for (int q = 0; q < 4; ++q) {
          acc[0][rq * 4 + q] += w.x * zz[q];
          acc[1][rq * 4 + q] += w.y * zz[q];
          acc[2][rq * 4 + q] += w.z * zz[q];
          acc[3][rq * 4 + q] += w.w * zz[q];
        }
      }
    }
  }
  const float4 bv = *reinterpret_cast<const float4*>(bi + d0);
  const float bx = cih ? 0.f : bv.x, by = cih ? 0.f : bv.y;
  const float bz = cih ? 0.f : bv.z, bw = cih ? 0.f : bv.w;
#pragma unroll
  for (int r = 0; r < 8; ++r) {
    float* zr = zd + (size_t)(n0 + r0 + r) * DDIM + d0;
    atomicAdd(zr + 0, acc[0][r] + bx);
    atomicAdd(zr + 1, acc[1][r] + by);
    atomicAdd(zr + 2, acc[2][r] + bz);
    atomicAdd(zr + 3, acc[3][r] + bw);
  }
}

// ================= flashS: swapped QK MFMA + gumbel + P store + row stats ====
// grid 512 = nb(32) x kq(16) via XCD swizzle; block 512 = 8 waves.
// Output S^T: lane col = n (fixed row of P per lane), regs = 16 kcl.
#define FSS(KT, CUR, UC, UN)                                                   \
  {                                                                            \
    const int k0 = kbase + (KT) * 32;                                          \
    __syncthreads(); /* Es[CUR] staged + UC landed (drained here) */           \
    if ((KT) < 15) {                                                           \
      _Pragma("unroll")                                                        \
      for (int pp = 0; pp < 2; ++pp) {                                         \
        const int q = tid + pp * 512, r = q >> 5, c = q & 31;                  \
        gload16(Eb + (size_t)(k0 + 32 + r) * 256 + (size_t)(c ^ (r & 7)) * 8,  \
                &Es[(1 - (CUR)) * 8192 + q * 8]);                              \
      }                                                                        \
      const float* ubn = ubase + k0 + 32 + 4 * half;                           \
      _Pragma("unroll")                                                        \
      for (int q = 0; q < 4; ++q)                                              \
        UN[q] = *reinterpret_cast<const float4*>(ubn + q * 8);                 \
    }                                                                          \
    const ushort* Ecur = Es + (CUR) * 8192;                                    \
    f32x16 acc;                                                                \
    _Pragma("unroll")                                                          \
    for (int i = 0; i < 16; ++i) acc[i] = 0.f;                                 \
    _Pragma("unroll")                                                          \
    for (int ks = 0; ks < 16; ++ks) {                                          \
      const int cc = (ks * 2 + half) ^ (r31 & 7);                              \
      const short8v Af =                                                       \
          *reinterpret_cast<const short8v*>(Ecur + r31 * 256 + cc * 8);        \
      acc = __builtin_amdgcn_mfma_f32_32x32x16_bf16(Af, ZB[ks], acc, 0, 0, 0); \
    }                                                                          \
    ushort* pdst = P + (size_t)n * KCL + k0 + 4 * half;                        \
    _Pragma("unroll")                                                          \
    for (int q = 0; q < 4; ++q) {                                              \
      const float uu[4] = {UC[q].x, UC[q].y, UC[q].z, UC[q].w};                \
      short4v st;                                                              \
      _Pragma("unroll")                                                        \
      for (int j = 0; j < 4; ++j) {                                            \
        const int reg = q * 4 + j;                                             \
        const int kcl = k0 + q * 8 + 4 * half + j;                             \
        const float ce = c2s[kcl - kbase];                                     \
        const float D = 1e-10f - __logf(uu[j] + 1e-10f);                       \
        const float pe = __fdividef(__expf(fmaf(acc[reg], 2.f, ce)), D);       \
        psum += pe;                                                            \
        const bool cA = pe > b0v, cB = pe > b1v;                               \
        const float nv = cA ? b0v : pe; const int ni = cA ? b0i : kcl;         \
        b1v = cB ? nv : b1v; b1i = cB ? ni : b1i;                              \
        b0v = cA ? pe : b0v; b0i = cA ? kcl : b0i;                             \
        st[j] = (short)f2bf(pe);                                               \
      }                                                                        \
      *reinterpret_cast<short4v*>(pdst + q * 8) = st;                          \
    }                                                                          \
  }

__global__ __launch_bounds__(512, 2) void flashS_kernel(
    const ushort* __restrict__ ZDB, const float* __restrict__ u,
    const ushort* __restrict__ Eb, const float* __restrict__ c2,
    ushort* __restrict__ P, float* __restrict__ lsp,
    float* __restrict__ candv, int* __restrict__ candi) {
  __shared__ ushort Es[2 * 32 * 256];   // dbuf [32 kcl][256 d], swizzled, 32KB
  __shared__ float c2s[512];
  const int tid = threadIdx.x;
  const int l = tid & 63, w = tid >> 6;
  const int half = l >> 5;
  const int swz = (blockIdx.x & 7) * 64 + (blockIdx.x >> 3);
  const int nb = swz & 31, kq = swz >> 5;
  const int n0 = nb * 256;
  const int kbase = kq * 512;
  const int r31 = l & 31;
  const int n = n0 + w * 32 + r31;     // lane's P row (fixed)

  // B-frags: z row n, 16 frags of 8 bf16 (d = ks*16 + half*8 ..)
  short8v ZB[16];
  {
    const ushort* zr = ZDB + (size_t)n * DDIM + half * 8;
#pragma unroll
    for (int ks = 0; ks < 16; ++ks)
      ZB[ks] = *reinterpret_cast<const short8v*>(zr + ks * 16);
  }

  const float* ubase = u + ((size_t)n << 13);
  c2s[tid] = c2[kbase + tid];

  // prologue: stage kt=0 into buf 0, load u for kt=0
#pragma unroll
  for (int pp = 0; pp < 2; ++pp) {
    const int q = tid + pp * 512, r = q >> 5, c = q & 31;
    gload16(Eb + (size_t)(kbase + r) * 256 + (size_t)(c ^ (r & 7)) * 8, &Es[q * 8]);
  }
  float4 uA[4], uB[4];
  {
    const float* ub = ubase + kbase + 4 * half;
#pragma unroll
    for (int q = 0; q < 4; ++q)
      uA[q] = *reinterpret_cast<const float4*>(ub + q * 8);
  }

  float psum = 0.f;
  float b0v = -1.f, b1v = -1.f;
  int b0i = 0x7fffffff, b1i = 0x7fffffff;

  for (int kt2 = 0; kt2 < 16; kt2 += 2) {
    FSS(kt2, 0, uA, uB);
    FSS(kt2 + 1, 1, uB, uA);
  }

  // pair merge (l ^ 32): full 512-col stats for row n
  psum += __shfl_xor(psum, 32);
  {
    const float ov0 = __shfl_xor(b0v, 32); const int oi0 = __shfl_xor(b0i, 32);
    const float ov1 = __shfl_xor(b1v, 32); const int oi1 = __shfl_xor(b1i, 32);
    {
      const bool cA = (ov0 > b0v) || (ov0 == b0v && oi0 < b0i);
      const bool cB = (ov0 > b1v) || (ov0 == b1v && oi0 < b1i);
      const float nv = cA ? b0v : ov0; const int ni = cA ? b0i : oi0;
      b1v = cB ? nv : b1v; b1i = cB ? ni : b1i;
      b0v = cA ? ov0 : b0v; b0i = cA ? oi0 : b0i;
    }
    {
      const bool cA = (ov1 > b0v) || (ov1 == b0v && oi1 < b0i);
      const bool cB = (ov1 > b1v) || (ov1 == b1v && oi1 < b1i);
      const float nv = cA ? b0v : ov1; const int ni = cA ? b0i : oi1;
      b1v = cB ? nv : b1v; b1i = cB ? ni : b1i;
      b0v = cA ? ov1 : b0v; b0i = cA ? oi1 : b0i;
    }
  }
  if (half == 0) {
    lsp[kq * NROWS + n] = psum;
    candv[(kq * 2 + 0) * NROWS + n] = b0v;
    candi[(kq * 2 + 0) * NROWS + n] = b0i;
    candv[(kq * 2 + 1) * NROWS + n] = b1v;
    candi[(kq * 2 + 1) * NROWS + n] = b1i;
  }
}

// ================= rowfin: merge candidates + lsum + exact argmax =============
__global__ __launch_bounds__(256) void rowfin_kernel(
    const float* __restrict__ lsp, const float* __restrict__ candv,
    const int* __restrict__ candi, const float* __restrict__ zd,
    const float* __restrict__ E, const float* __restrict__ e2,
    const float* __restrict__ u, float* __restrict__ linv,
    float* __restrict__ counts) {
  const int l = threadIdx.x & 63;
  const int w = threadIdx.x >> 6;
  const int n = blockIdx.x * 4 + w;

  float bv[4] = {-1.f, -1.f, -1.f, -1.f};
  int bi[4] = {0x7fffffff, 0x7fffffff, 0x7fffffff, 0x7fffffff};
  if (l < 32) { bv[0] = candv[l * NROWS + n]; bi[0] = candi[l * NROWS + n]; }
#pragma unroll
  for (int mk = 1; mk < 64; mk <<= 1) {
    float ov[4]; int oi[4];
#pragma unroll
    for (int i = 0; i < 4; ++i) { ov[i] = __shfl_xor(bv[i], mk); oi[i] = __shfl_xor(bi[i], mk); }
#pragma unroll
    for (int i = 0; i < 4; ++i) {
      const float f = ov[i]; const int kk = oi[i];
      const bool c0 = (f > bv[0]) || (f == bv[0] && kk < bi[0]);
      const bool c1 = (f > bv[1]) || (f == bv[1] && kk < bi[1]);
      const bool c2 = (f > bv[2]) || (f == bv[2] && kk < bi[2]);
      const bool c3 = (f > bv[3]) || (f == bv[3] && kk < bi[3]);
      const float n3 = c2 ? bv[2] : f; const int i3 = c2 ? bi[2] : kk;
      const float n2 = c1 ? bv[1] : f; const int i2 = c1 ? bi[1] : kk;
      const float n1 = c0 ? bv[0] : f; const int i1 = c0 ? bi[0] : kk;
      bv[3] = c3 ? n3 : bv[3]; bi[3] = c3 ? i3 : bi[3];
      bv[2] = c2 ? n2 : bv[2]; bi[2] = c2 ? i2 : bi[2];
      bv[1] = c1 ? n1 : bv[1]; bi[1] = c1 ? i1 : bi[1];
      bv[0] = c0 ? f : bv[0];  bi[0] = c0 ? kk : bi[0];
    }
  }
  // lsum: fixed-pattern tree over 16 partials (deterministic)
  float ls = (l < 16) ? lsp[l * NROWS + n] : 0.f;
#pragma unroll
  for (int mk = 1; mk <= 8; mk <<= 1) ls += __shfl_xor(ls, mk);
  // exact fp32 eval of 4 candidates
  const float4 zv = *reinterpret_cast<const float4*>(zd + (size_t)n * DDIM + l * 4);
  float best = -1e30f; int besti = 0x7fffffff;
#pragma unroll
  for (int c = 0; c < 4; ++c) {
    const int kc = bi[c];
    const float4 ev = *reinterpret_cast<const float4*>(E + (size_t)kc * DDIM + l * 4);
    float d = zv.x * ev.x + zv.y * ev.y + zv.z * ev.z + zv.w * ev.w;
#pragma unroll
    for (int mk = 1; mk < 64; mk <<= 1) d += __shfl_xor(d, mk);
    const float uu = u[(size_t)n * KCL + kc];
    const float D = 1e-10f - __logf(uu + 1e-10f);
    const float g = -__logf(D);
    const float lg = 2.f * d - e2[kc] + g;
    if (lg > best || (lg == best && kc < besti)) { best = lg; besti = kc; }
  }
  if (l == 0) {
    atomicAdd(&counts[besti], 1.f);
    linv[n] = 1.f / ls;
  }
}

// ================= pvS: parts[ks] = p @ E, dbuf gload_lds P + global ET ======
// grid 512 = nb(128) x ks(4) via XCD swizzle; block 512 = 8 waves; wave 32n x 64d.
__global__ __launch_bounds__(512, 2) void pvS_kernel(
    const ushort* __restrict__ P, const ushort* __restrict__ ET,
    const float* __restrict__ linv, float* __restrict__ parts,
    float* __restrict__ colsum) {
  __shared__ ushort ps[2][64 * 64];  // dbuf 16KB, chunk-swizzled
  __shared__ float linv_s[64];
  const int tid = threadIdx.x;
  const int l = tid & 63, w = tid >> 6;
  const int half = l >> 5;
  const int r31 = l & 31;
  const int swz = (blockIdx.x & 7) * 64 + (blockIdx.x >> 3);
  const int nb = swz & 127, ks = swz >> 7;
  const int n0 = nb * 64;
  const int kc0 = ks * 2048;
  const int nw = w & 1, dw = w >> 1;
  const int sr = tid >> 3, sc = tid & 7;   // staging row/chunk (1 load/thread)

  if (tid < 64) linv_s[tid] = linv[n0 + tid];

  f32x16 acc0, acc1;
#pragma unroll
  for (int i = 0; i < 16; ++i) { acc0[i] = 0.f; acc1[i] = 0.f; }

  // prologue: stage tile 0 into buf 0 (swizzled source -> linear dest)
  gload16(P + (size_t)(n0 + sr) * KCL + kc0 + (size_t)(sc ^ (sr & 7)) * 8,
          &ps[0][tid * 8]);

  for (int t = 0; t < 32; ++t) {
    const int cur = t & 1;
    const int kc = kc0 + t * 64;
    __syncthreads();  // ps[cur] staged + everyone done with ps[cur^1]
    if (t < 31) {
      gload16(P + (size_t)(n0 + sr) * KCL + kc + 64 + (size_t)(sc ^ (sr & 7)) * 8,
              &ps[1 - cur][tid * 8]);
    }
#pragma unroll
    for (int ksn = 0; ksn < 4; ++ksn) {
      const int cc = ksn * 2 + half;
      short8v a, b0, b1;
      {
        const int r = nw * 32 + r31;
        a = *reinterpret_cast<const short8v*>(&ps[cur][r * 64 + ((cc ^ (r & 7))) * 8]);
      }
      {
        const ushort* etb = ET + (size_t)(dw * 64 + r31) * KCL + kc + cc * 8;
        b0 = *reinterpret_cast<const short8v*>(etb);
        b1 = *reinterpret_cast<const short8v*>(etb + (size_t)32 * KCL);
      }
      acc0 = __builtin_amdgcn_mfma_f32_32x32x16_bf16(a, b0, acc0, 0, 0, 0);
      acc1 = __builtin_amdgcn_mfma_f32_32x32x16_bf16(a, b1, acc1, 0, 0, 0);
    }
    // fused colsum partial for this 64x64 tile (ps[cur] valid till next barrier)
    {
      const int c = tid >> 3;
      const int rb = tid & 7;
      float csp = 0.f;
#pragma unroll
      for (int r8 = 0; r8 < 8; ++r8) {
        const int r = rb + r8 * 8;
        const int chunk = (c >> 3) ^ (r & 7);
        csp += bf2f(ps[cur][r * 64 + chunk * 8 + (c & 7)]) * linv_s[r];
      }
      csp += __shfl_xor(csp, 1);
      csp += __shfl_xor(csp, 2);
      csp += __shfl_xor(csp, 4);
      if (rb == 0) atomicAdd(&colsum[kc + c], csp);
    }
  }
  float* pbase = parts + (size_t)ks * NROWS * DDIM;
#pragma unroll
  for (int reg = 0; reg < 16; ++reg) {
    const int dr = (reg & 3) + 8 * (reg >> 2) + 4 * half;
    float* zr = pbase + (size_t)(n0 + nw * 32 + dr) * DDIM + dw * 64 + r31;
    zr[0]  = acc0[reg];
    zr[32] = acc1[reg];
  }
}

// ================= zqred: sum splits, scale by linv, write zq, vq partial =====
__global__ __launch_bounds__(256) void zqred_kernel(const float* __restrict__ parts,
                                                    const float* __restrict__ linv,
                                                    const float* __restrict__ zd,
                                                    float* __restrict__ zq,
                                                    float* __restrict__ vqs) {
  const size_t i = ((size_t)blockIdx.x * 256 + threadIdx.x) * 8;
  const int n = (int)(i >> 8);
  const float lv = linv[n];
  float s = 0.f;
#pragma unroll
  for (int j = 0; j < 8; j += 4) {
    float4 p0 = *reinterpret_cast<const float4*>(parts + i + j);
    const float4 p1 = *reinterpret_cast<const float4*>(parts + i + j + (size_t)NROWS * DDIM);
    const float4 p2 = *reinterpret_cast<const float4*>(parts + i + j + (size_t)2 * NROWS * DDIM);
    const float4 p3 = *reinterpret_cast<const float4*>(parts + i + j + (size_t)3 * NROWS * DDIM);
    const float4 a = *reinterpret_cast<const float4*>(zd + i + j);
    float4 o;
    o.x = (p0.x + p1.x + p2.x + p3.x) * lv;
    o.y = (p0.y + p1.y + p2.y + p3.y) * lv;
    o.z = (p0.z + p1.z + p2.z + p3.z) * lv;
    o.w = (p0.w + p1.w + p2.w + p3.w) * lv;
    *reinterpret_cast<float4*>(zq + i + j) = o;
    const float dx = a.x - o.x, dy = a.y - o.y, dz = a.z - o.z, dw = a.w - o.w;
    s += dx * dx + dy * dy + dz * dz + dw * dw;
  }
#pragma unroll
  for (int mk = 1; mk < 64; mk <<= 1) s += __shfl_xor(s, mk);
  if ((threadIdx.x & 63) == 0) atomicAdd(vqs, s);
}

// ================= outproj via MFMA =================
__global__ __launch_bounds__(256) void outproj2_kernel(const float* __restrict__ zq,
                                                       const ushort* __restrict__ Wob,
                                                       const float* __restrict__ bo,
                                                       float* __restrict__ outp) {
  extern __shared__ char smem[];
  ushort* zs = (ushort*)smem;
  ushort* wsld = zs + 64 * 256;
  const int tid = threadIdx.x;
  const int l = tid & 63, w = tid >> 6;
  const int half = l >> 5;
  const int nb = blockIdx.x >> 4, ob = blockIdx.x & 15;
  const int n0 = nb * 64, o0 = ob * 64;
  const int nw = w & 1, ow = w >> 1;
  {
    const int row = tid >> 2, seg = tid & 3;
    const float* zr = zq + (size_t)(n0 + row) * DDIM + seg * 64;
    const ushort* wr = Wob + (size_t)(o0 + row) * DDIM + seg * 64;
#pragma unroll
    for (int g = 0; g < 8; ++g) {
      const float4 a = *reinterpret_cast<const float4*>(zr + g * 8);
      const float4 b = *reinterpret_cast<const float4*>(zr + g * 8 + 4);
      const int c = seg * 8 + g;
      *reinterpret_cast<short8v*>(zs + row * 256 + ((c ^ (row & 7))) * 8) = pack8(a, b);
      const short8v wv = *reinterpret_cast<const short8v*>(wr + g * 8);
      *reinterpret_cast<short8v*>(wsld + row * 256 + ((c ^ (row & 7))) * 8) = wv;
    }
  }
  __syncthreads();
  f32x16 acc;
#pragma unroll
  for (int i = 0; i < 16; ++i) acc[i] = 0.f;
#pragma unroll
  for (int ksn = 0; ksn < 16; ++ksn) {
    const int cc = ksn * 2 + half;
    const int ra = nw * 32 + (l & 31);
    const int rb = ow * 32 + (l & 31);
    const short8v a = *reinterpret_cast<const short8v*>(zs + ra * 256 + ((cc ^ (ra & 7))) * 8);
    const short8v b = *reinterpret_cast<const short8v*>(wsld + rb * 256 + ((cc ^ (rb & 7))) * 8);
    acc = __builtin_amdgcn_mfma_f32_32x32x16_bf16(a, b, acc, 0, 0, 0);
  }
  const int o = o0 + ow * 32 + (l & 31);
  const float bvv = bo[o];
  const int nbase = n0 + nw * 32 + 4 * half;
#pragma unroll
  for (int rq = 0; rq < 4; ++rq) {
    const int n = nbase + rq * 8;
    const int b = n >> 11;
    const int tt = n & 2047;
    float4 ov;
    ov.x = acc[rq * 4 + 0] + bvv;
    ov.y = acc[rq * 4 + 1] + bvv;
    ov.z = acc[rq * 4 + 2] + bvv;
    ov.w = acc[rq * 4 + 3] + bvv;
    *reinterpret_cast<float4*>(outp + ((size_t)b * CIN + o) * TSEQ + tt) = ov;
  }
}

// ================= round-1 fallback flash (fp32) =================
template <bool STORE_LG>
__global__ __launch_bounds__(512) void flash_kernel(
    const float* __restrict__ zd, const float* __restrict__ u,
    const float* __restrict__ E, const float* __restrict__ e2g,
    float* __restrict__ zq, float* __restrict__ colsum,
    float* __restrict__ counts, float* __restrict__ vqsum,
    float* __restrict__ linvg, __half* __restrict__ lgbuf) {
  extern __shared__ float lds[];
  float* zs = lds;
  float* es = zs + 32 * 260;
  float* e2t = es + 64 * 260;
  float* cst = e2t + 64;
  float* red = cst + 64;

  const int tid = threadIdx.x;
  const int lane = tid & 63;
  const int wv = tid >> 6;
  const int r = (lane >> 4) & 3;
  const int kg = lane & 15;
  const int row = wv * 4 + r;
  const int n0 = blockIdx.x * 32;
  const int n = n0 + row;

  {
    const int rr = tid >> 4;
    const int iq = tid & 15;
#pragma unroll
    for (int p = 0; p < 4; ++p) {
      const int i = iq * 16 + p * 4;
      *reinterpret_cast<float4*>(&zs[rr * 260 + i]) =
          *reinterpret_cast<const float4*>(zd + (size_t)(n0 + rr) * DDIM + i);
    }
  }

  float4 accp[4];
#pragma unroll
  for (int s = 0; s < 4; ++s) accp[s] = make_float4(0.f, 0.f, 0.f, 0.f);
  float lsum = 0.f;
  float best = -1e30f;
  int bidx = 0;

  const float* zrow = zs + row * 260;

  for (int t = 0; t < KCL / 64; ++t) {
    const int k0 = t * 64;
    __syncthreads();
    {
      const int iq = tid & 15;
#pragma unroll
      for (int pp = 0; pp < 2; ++pp) {
        const int kk = (tid >> 4) + pp * 32;
#pragma unroll
        for (int p = 0; p < 4; ++p) {
          const int i = iq * 16 + p * 4;
          *reinterpret_cast<float4*>(&es[kk * 260 + i]) =
              *reinterpret_cast<const float4*>(E + (size_t)(k0 + kk) * DDIM + i);
        }
      }
      if (tid < 64) e2t[tid] = e2g[k0 + tid];
    }
    __syncthreads();

    float acc4[4] = {0.f, 0.f, 0.f, 0.f};
#pragma unroll 4
    for (int i = 0; i < DDIM; i += 4) {
      const float4 zv = *reinterpret_cast<const float4*>(zrow + i);
#pragma unroll
      for (int jj = 0; jj < 4; ++jj) {
        const float4 ev = *reinterpret_cast<const float4*>(&es[(kg + jj * 16) * 260 + i]);
        acc4[jj] += zv.x * ev.x + zv.y * ev.y + zv.z * ev.z + zv.w * ev.w;
      }
    }

    float p4[4];
    float tmax = -1e30f;
    int tidx = 0;
#pragma unroll
    for (int jj = 0; jj < 4; ++jj) {
      const int kk = kg + jj * 16;
      const float uu = u[(size_t)n * KCL + k0 + kk];
      const float g = -__logf(-__logf(uu + EPSL) + EPSL);
      const float lt = 2.f * acc4[jj] - e2t[kk] + g - MHAT;
      const float pe = __expf(lt);
      p4[jj] = pe;
      lsum += pe;
      if (lt > tmax) { tmax = lt; tidx = k0 + kk; }
    }
#pragma unroll
    for (int mk = 1; mk <= 8; mk <<= 1) {
      const float ov = __shfl_xor(tmax, mk);
      const int oi = __shfl_xor(tidx, mk);
      if (ov > tmax || (ov == tmax && oi < tidx)) { tmax = ov; tidx = oi; }
    }
    if (tmax > best) { best = tmax; bidx = tidx; }

#pragma unroll
    for (int jj = 0; jj < 4; ++jj) {
#pragma unroll 4
      for (int q = 0; q < 16; ++q) {
        const int kk = jj * 16 + q;
        const float yv = __shfl(p4[jj], (lane & 48) | q);
        const float* erow = &es[kk * 260 + kg * 16];
#pragma unroll
        for (int s = 0; s < 4; ++s) {
          const int c = (s + kg) & 3;
          const float4 ev = *reinterpret_cast<const float4*>(erow + c * 4);
          accp[s].x += yv * ev.x;
          accp[s].y += yv * ev.y;
          accp[s].z += yv * ev.z;
          accp[s].w += yv * ev.w;
        }
      }
    }
  }

#pragma unroll
  for (int mk = 1; mk <= 8; mk <<= 1) lsum += __shfl_xor(lsum, mk);
  const float linv = 1.0f / lsum;

  if (kg == 0) {
    atomicAdd(&counts[bidx], 1.0f);
    linvg[n] = linv;
  }

  float vqp = 0.f;
#pragma unroll
  for (int s = 0; s < 4; ++s) {
    const int c = (s + kg) & 3;
    const int d = kg * 16 + c * 4;
    float4 o;
    o.x = accp[s].x * linv;
    o.y = accp[s].y * linv;
    o.z = accp[s].z * linv;
    o.w = accp[s].w * linv;
    *reinterpret_cast<float4*>(zq + (size_t)n * DDIM + d) = o;
    const float4 zv = *reinterpret_cast<const float4*>(zrow + d);
    const float dx = zv.x - o.x, dy = zv.y - o.y, dz = zv.z - o.z, dw = zv.w - o.w;
    vqp += dx * dx + dy * dy + dz * dz + dw * dw;
  }
#pragma unroll
  for (int mk = 1; mk <= 32; mk <<= 1) vqp += __shfl_xor(vqp, mk);
  if (lane == 0) red[wv] = vqp;
  __syncthreads();
  if (tid == 0) {
    float s = 0.f;
#pragma unroll
    for (int ww = 0; ww < 8; ++ww) s += red[ww];
    atomicAdd(vqsum, s);
  }

  if (!STORE_LG) {
    if (tid < 64) cst[tid] = 0.f;
    for (int t = 0; t < KCL / 64; ++t) {
      const int k0 = t * 64;
      __syncthreads();
      {
        const int iq = tid & 15;
#pragma unroll
        for (int pp = 0; pp < 2; ++pp) {
          const int kk = (tid >> 4) + pp * 32;
#pragma unroll
          for (int p = 0; p < 4; ++p) {
            const int i = iq * 16 + p * 4;
            *reinterpret_cast<float4*>(&es[kk * 260 + i]) =
                *reinterpret_cast<const float4*>(E + (size_t)(k0 + kk) * DDIM + i);
          }
        }
        if (tid < 64) e2t[tid] = e2g[k0 + tid];
      }
      __syncthreads();
      float acc4[4] = {0.f, 0.f, 0.f, 0.f};
#pragma unroll 4
      for (int i = 0; i < DDIM; i += 4) {
        const float4 zv = *reinterpret_cast<const float4*>(zrow + i);
#pragma unroll
        for (int jj = 0; jj < 4; ++jj) {
          const float4 ev = *reinterpret_cast<const float4*>(&es[(kg + jj * 16) * 260 + i]);
          acc4[jj] += zv.x * ev.x + zv.y * ev.y + zv.z * ev.z + zv.w * ev.w;
        }
      }
      float cs4[4];
#pragma unroll
      for (int jj = 0; jj < 4; ++jj) {
        const int kk = kg + jj * 16;
        const float uu = u[(size_t)n * KCL + k0 + kk];
        const float g = -__logf(-__logf(uu + EPSL) + EPSL);
        const float lt = 2.f * acc4[jj] - e2t[kk] + g - MHAT;
        cs4[jj] = __expf(lt) * linv;
      }
#pragma unroll
      for (int mk = 16; mk <= 32; mk <<= 1)
#pragma unroll
        for (int jj = 0; jj < 4; ++jj) cs4[jj] += __shfl_xor(cs4[jj], mk);
      if (lane < 16) {
#pragma unroll
        for (int jj = 0; jj < 4; ++jj) atomicAdd(&cst[kg + jj * 16], cs4[jj]);
      }
      __syncthreads();
      if (tid < 64) {
        atomicAdd(&colsum[k0 + tid], cst[tid]);
        cst[tid] = 0.f;
      }
    }
  }
}

// ================= round-1 outproj (fp32, fallback) =================
__global__ __launch_bounds__(256) void outproj_kernel(const float* __restrict__ zq,
                                                      const float* __restrict__ Wo,
                                                      const float* __restrict__ bo,
                                                      float* __restrict__ outp) {
  __shared__ float wo_s[32 * 260];
  __shared__ float zc[32 * 68];
  const int tid = threadIdx.x;
  const int n0 = (blockIdx.x >> 2) * 64;
  const int ot = (blockIdx.x & 3) * 256;
  const int b = n0 / TSEQ;
  const int t0 = n0 % TSEQ;

  const int og = tid & 63;
  const int o0 = og * 4;
  const int wv = tid >> 6;
  const int r0 = wv * 16;

  float acc[4][16];
#pragma unroll
  for (int c = 0; c < 4; ++c)
#pragma unroll
    for (int r = 0; r < 16; ++r) acc[c][r] = 0.f;

  for (int dd = 0; dd < DDIM; dd += 32) {
    __syncthreads();
    {
      const int ccq = (tid & 7) * 4;
      const int oq = tid >> 3;
#pragma unroll
      for (int p = 0; p < 8; ++p) {
        const int oo = oq + p * 32;
        const float4 w = *reinterpret_cast<const float4*>(Wo + (size_t)(ot + oo) * DDIM + dd + ccq);
        wo_s[(ccq + 0) * 260 + oo] = w.x;
        wo_s[(ccq + 1) * 260 + oo] = w.y;
        wo_s[(ccq + 2) * 260 + oo] = w.z;
        wo_s[(ccq + 3) * 260 + oo] = w.w;
      }
#pragma unroll
      for (int p = 0; p < 2; ++p) {
        const int rr = oq + p * 32;
        const float4 v = *reinterpret_cast<const float4*>(zq + (size_t)(n0 + rr) * DDIM + dd + ccq);
        zc[(ccq + 0) * 68 + rr] = v.x;
        zc[(ccq + 1) * 68 + rr] = v.y;
        zc[(ccq + 2) * 68 + rr] = v.z;
        zc[(ccq + 3) * 68 + rr] = v.w;
      }
    }
    __syncthreads();
#pragma unroll
    for (int cc = 0; cc < 32; ++cc) {
      const float4 w = *reinterpret_cast<const float4*>(&wo_s[cc * 260 + o0]);
#pragma unroll
      for (int rq = 0; rq < 4; ++rq) {
        const float4 zv = *reinterpret_cast<const float4*>(&zc[cc * 68 + r0 + rq * 4]);
        const float zz[4] = {zv.x, zv.y, zv.z, zv.w};
#pragma unroll
        for (int q = 0; q < 4; ++q) {
          acc[0][rq * 4 + q] += w.x * zz[q];
          acc[1][rq * 4 + q] += w.y * zz[q];
          acc[2][rq * 4 + q] += w.z * zz[q];
          acc[3][rq * 4 + q] += w.w * zz[q];
        }
      }
    }
  }
  const float4 bv = *reinterpret_cast<const float4*>(bo + ot + o0);
  float* ob = outp + (size_t)b * CIN * TSEQ + t0;
  const float bb[4] = {bv.x, bv.y, bv.z, bv.w};
#pragma unroll
  for (int c = 0; c < 4; ++c) {
#pragma unroll
    for (int rq = 0; rq < 4; ++rq) {
      float4 o;
      o.x = acc[c][rq * 4 + 0] + bb[c];
      o.y = acc[c][rq * 4 + 1] + bb[c];
      o.z = acc[c][rq * 4 + 2] + bb[c];
      o.w = acc[c][rq * 4 + 3] + bb[c];
      *reinterpret_cast<float4*>(ob + (size_t)(ot + o0 + c) * TSEQ + r0 + rq * 4) = o;
    }
  }
}

// ================= finalize (shared) =================
__global__ __launch_bounds__(256) void finalize_kernel(
    const float* __restrict__ colsum, const float* __restrict__ counts,
    const float* __restrict__ vqsum, const float* __restrict__ csin,
    float* __restrict__ outsc, float* __restrict__ ncs) {
  __shared__ float rS[3][4];
  const int tid = threadIdx.x;
  const int lane = tid & 63;
  const int wv = tid >> 6;
  float sLog = 0.f, sH = 0.f, sAct = 0.f;
  for (int k = tid; k < KCL; k += 256) {
    const float avg = colsum[k] * (1.0f / NROWS);
    sLog += __logf(avg + EPSL);
    const float pb = counts[k] * (1.0f / NROWS);
    sH += pb * __logf(pb + EPSL);
    sAct += (csin[k] > 2.0f) ? 1.f : 0.f;
    ncs[k] = csin[k] * 0.99f + counts[k] * 0.01f;
  }
#pragma unroll
  for (int mk = 1; mk <= 32; mk <<= 1) {
    sLog += __shfl_xor(sLog, mk);
    sH += __shfl_xor(sH, mk);
    sAct += __shfl_xor(sAct, mk);
  }
  if (lane == 0) { rS[0][wv] = sLog; rS[1][wv] = sH; rS[2][wv] = sAct; }
  __syncthreads();
  if (tid == 0) {
    float SL = 0.f, SH = 0.f, SA = 0.f;
#pragma unroll
    for (int w = 0; w < 4; ++w) { SL += rS[0][w]; SH += rS[1][w]; SA += rS[2][w]; }
    outsc[0] = vqsum[0] * (1.0f / ((float)NROWS * (float)DDIM));
    outsc[1] = (float)NROWS * __logf(1.0f / (float)KCL) - SL;
    outsc[2] = __expf(-SH);
    outsc[3] = SA;
  }
}

extern "C" void kernel_launch(void* const* d_in, const int* in_sizes, int n_in,
                              void* d_out, int out_size, void* d_ws, size_t ws_size,
                              hipStream_t stream) {
  (void)in_sizes; (void)n_in; (void)out_size;
  const float* z = (const float*)d_in[0];
  const float* u = (const float*)d_in[1];
  const float* Wi = (const float*)d_in[2];
  const float* bi = (const float*)d_in[3];
  const float* Wo = (const float*)d_in[4];
  const float* bo = (const float*)d_in[5];
  const float* E = (const float*)d_in[6];
  const float* csin = (const float*)d_in[7];
  float* outp = (float*)d_out;
  float* ws = (float*)d_ws;

  const size_t needNew = (size_t)ENDW * 4;
  if (ws_size >= needNew) {
    ushort* EB = (ushort*)(ws + EBW);
    ushort* ET = (ushort*)(ws + ETW);
    ushort* WOB = (ushort*)(ws + WOBW);
    ushort* ZDB = (ushort*)(ws + ZDBW);
    ushort* P = (ushort*)(ws + PW);

    hipMemsetAsync((void*)(ws + CSUMW), 0, (size_t)(2 * KCL + 64) * 4, stream);
    hipMemsetAsync((void*)(ws + ZD2W), 0, (size_t)NROWS * DDIM * 4, stream);

    e2c2_kernel<<<KCL / 64, 256, 0, stream>>>(E, ws + E2W, ws + C2W);
    etprep_kernel<<<512, 256, 0, stream>>>(E, ET, EB);
    cvtwob_kernel<<<128, 256, 0, stream>>>(Wo, WOB);
    inproj32_kernel<<<512, 256, 0, stream>>>(z, Wi, bi, ws + ZD2W);
    cvtwob_kernel<<<1024, 256, 0, stream>>>(ws + ZD2W, ZDB);  // zd -> bf16

    flashS_kernel<<<512, 512, 0, stream>>>(ZDB, u, EB, ws + C2W, P,
                                           ws + LSPW, ws + CVW, (int*)(ws + CIW));
    rowfin_kernel<<<NROWS / 4, 256, 0, stream>>>(ws + LSPW, ws + CVW,
                                                 (const int*)(ws + CIW),
                                                 ws + ZD2W, E, ws + E2W, u,
                                                 ws + LINVW, ws + CNTW);
    // split-K partials scribbled into d_out (exactly OUT_SC floats), then
    // reduced into zq; outproj2 overwrites d_out afterwards. colsum fused here.
    pvS_kernel<<<512, 512, 0, stream>>>(P, ET, ws + LINVW, outp, ws + CSUMW);
    zqred_kernel<<<1024, 256, 0, stream>>>(outp, ws + LINVW, ws + ZD2W,
                                           ws + ZQ2W, ws + VQW);

    hipFuncSetAttribute(reinterpret_cast<const void*>(&outproj2_kernel),
                        hipFuncAttributeMaxDynamicSharedMemorySize, 65536);
    outproj2_kernel<<<2048, 256, 65536, stream>>>(ws + ZQ2W, WOB, bo, outp);
    finalize_kernel<<<1, 256, 0, stream>>>(ws + CSUMW, ws + CNTW, ws + VQW,
                                           csin, outp + OUT_SC, outp + OUT_SC + 4);
  } else {
    hipMemsetAsync((void*)(ws + CS_OFF), 0, (size_t)(2 * KCL + 1) * sizeof(float), stream);
    hipMemsetAsync((void*)(ws + ZD_OFF), 0, (size_t)NROWS * DDIM * 4, stream);
    e2_kernel<<<KCL / 64, 256, 0, stream>>>(E, ws + E2_OFF);
    inproj32_kernel<<<512, 256, 0, stream>>>(z, Wi, bi, ws + ZD_OFF);
    const int ldsB = (32 * 260 + 64 * 260 + 64 + 64 + 16) * 4;
    hipFuncSetAttribute(reinterpret_cast<const void*>(&flash_kernel<false>),
                        hipFuncAttributeMaxDynamicSharedMemorySize, ldsB);
    flash_kernel<false><<<NROWS / 32, 512, ldsB, stream>>>(
        ws + ZD_OFF, u, E, ws + E2_OFF, ws + ZQ_OFF, ws + CS_OFF, ws + CNT_OFF,
        ws + VQ_OFF, ws + LINV_OFF, (__half*)nullptr);
    outproj_kernel<<<(NROWS / 64) * 4, 256, 0, stream>>>(ws + ZQ_OFF, Wo, bo, outp);
    finalize_kernel<<<1, 256, 0, stream>>>(ws + CS_OFF, ws + CNT_OFF, ws + VQ_OFF,
                                           csin, outp + OUT_SC, outp + OUT_SC + 4);
  }
}

// Round 10
// 606.675 us; speedup vs baseline: 1.0011x; 1.0011x over previous
//
#include <hip/hip_runtime.h>
#include <hip/hip_fp16.h>

// VectorQuantize forward, round 8:
// - flashS: swapped-operand QK (S^T = mfma(E, z)) -> lane owns ONE row n.
//   u loads 4x float4 (was 16 scalars), P stores 4x 8B (was 16x 2B),
//   row-stats (lsum + top-2) fused lane-locally; per-block stats to fixed
//   slots (deterministic). rowpass + cvtzf + ZF buffer eliminated.
// - rowfin: merge 32 candidates/row + fixed-order lsum + exact fp32 argmax.
// - pvS: pv2 with flash4-style gload_lds dbuf for P (ONE barrier/iter) and
//   ET B-frags direct from global (L2-resident) -> es LDS (64KB) deleted.
// - inproj32, zqred, outproj2, finalize, prep kernels unchanged.

#define NROWS 8192
#define KCL   8192
#define DDIM  256
#define CIN   1024
#define TSEQ  2048
#define EPSL  1e-10f
#define MHAT  (-140.0f)

#define OUT_SC   (4*CIN*TSEQ)   // 8388608 == 4 * NROWS * DDIM (split-K parts fit)

// ---- old-path (round-1 fallback) ws offsets ----
#define ZD_OFF   0
#define ZQ_OFF   (NROWS*DDIM)
#define E2_OFF   (2*NROWS*DDIM)
#define CS_OFF   (E2_OFF + KCL)
#define CNT_OFF  (CS_OFF + KCL)
#define VQ_OFF   (CNT_OFF + KCL)
#define LINV_OFF (VQ_OFF + 4)

// ---- new-path ws offsets (float words) ----
#define ZD2W   0
#define ZQ2W   2097152
#define EBW    4194304
#define ETW    5242880
#define WOBW   6291456
#define ZDBW   6422528          // bf16 zd [N][D] (4MB; replaces ZF)
#define E2W    7471104
#define C2W    7479296
#define LINVW  7487488
#define CSUMW  7495680
#define CNTW   7503872
#define VQW    7512064
#define PW     7512128
#define ENDW   (PW + 33554432)
// transient stats live in the zq region (consumed by rowfin before zqred
// overwrites with zq): lsumpart[16][8192], candv[32][8192], candi[32][8192]
#define LSPW   ZQ2W
#define CVW    (ZQ2W + 131072)
#define CIW    (ZQ2W + 393216)

using short8v = __attribute__((ext_vector_type(8))) short;
using short4v = __attribute__((ext_vector_type(4))) short;
using f32x16  = __attribute__((ext_vector_type(16))) float;

__device__ __forceinline__ ushort f2bf(float f) {
  unsigned int x = __float_as_uint(f);
  return (ushort)((x + 0x7FFFu + ((x >> 16) & 1u)) >> 16);
}
__device__ __forceinline__ float bf2f(ushort h) {
  return __uint_as_float(((unsigned int)h) << 16);
}
__device__ __forceinline__ short8v pack8(float4 a, float4 b) {
  short8v v;
  v[0] = (short)f2bf(a.x); v[1] = (short)f2bf(a.y);
  v[2] = (short)f2bf(a.z); v[3] = (short)f2bf(a.w);
  v[4] = (short)f2bf(b.x); v[5] = (short)f2bf(b.y);
  v[6] = (short)f2bf(b.z); v[7] = (short)f2bf(b.w);
  return v;
}
__device__ __forceinline__ void gload16(const void* g, void* l) {
  __builtin_amdgcn_global_load_lds(
      (const __attribute__((address_space(1))) unsigned int*)g,
      (__attribute__((address_space(3))) unsigned int*)l, 16, 0, 0);
}

// ================= shared prep =================

__global__ __launch_bounds__(256) void e2_kernel(const float* __restrict__ E,
                                                 float* __restrict__ e2) {
  const int tid = threadIdx.x;
  const int k = blockIdx.x * 64 + (tid >> 2);
  const int p = tid & 3;
  const float* row = E + (size_t)k * DDIM + p * 64;
  float s = 0.f;
#pragma unroll
  for (int j = 0; j < 16; ++j) {
    const float4 v = *reinterpret_cast<const float4*>(row + j * 4);
    s += v.x * v.x + v.y * v.y + v.z * v.z + v.w * v.w;
  }
  s += __shfl_xor(s, 1);
  s += __shfl_xor(s, 2);
  if (p == 0) e2[k] = s;
}

__global__ __launch_bounds__(256) void e2c2_kernel(const float* __restrict__ E,
                                                   float* __restrict__ e2,
                                                   float* __restrict__ c2) {
  const int tid = threadIdx.x;
  const int k = blockIdx.x * 64 + (tid >> 2);
  const int p = tid & 3;
  const float* row = E + (size_t)k * DDIM + p * 64;
  float s = 0.f;
#pragma unroll
  for (int j = 0; j < 16; ++j) {
    const float4 v = *reinterpret_cast<const float4*>(row + j * 4);
    s += v.x * v.x + v.y * v.y + v.z * v.z + v.w * v.w;
  }
  s += __shfl_xor(s, 1);
  s += __shfl_xor(s, 2);
  if (p == 0) { e2[k] = s; c2[k] = -s - MHAT; }
}

// generic f32 -> bf16 cast (used for Wo and for zd -> ZDB)
__global__ __launch_bounds__(256) void cvtwob_kernel(const float* __restrict__ W,
                                                     ushort* __restrict__ Wb) {
  const size_t i = ((size_t)blockIdx.x * 256 + threadIdx.x) * 8;
  const float4 a = *reinterpret_cast<const float4*>(W + i);
  const float4 b = *reinterpret_cast<const float4*>(W + i + 4);
  *reinterpret_cast<short8v*>(Wb + i) = pack8(a, b);
}

// E [K][D] f32 -> ET [D][K] bf16 AND EB [K][D] bf16 (fused)
__global__ __launch_bounds__(256) void etprep_kernel(const float* __restrict__ E,
                                                     ushort* __restrict__ ET,
                                                     ushort* __restrict__ EB) {
  __shared__ float tb[64 * 68];
  const int t = threadIdx.x;
  const int kb = (blockIdx.x & 127) * 64;
  const int db = (blockIdx.x >> 7) * 64;
#pragma unroll
  for (int it = 0; it < 4; ++it) {
    const int r = (t >> 4) + it * 16;
    const int c = (t & 15) * 4;
    const float4 v = *reinterpret_cast<const float4*>(E + (size_t)(kb + r) * DDIM + db + c);
    tb[r * 68 + c] = v.x; tb[r * 68 + c + 1] = v.y;
    tb[r * 68 + c + 2] = v.z; tb[r * 68 + c + 3] = v.w;
    short4v o;
    o[0] = (short)f2bf(v.x); o[1] = (short)f2bf(v.y);
    o[2] = (short)f2bf(v.z); o[3] = (short)f2bf(v.w);
    *reinterpret_cast<short4v*>(EB + (size_t)(kb + r) * DDIM + db + c) = o;
  }
  __syncthreads();
  const int dl = t >> 2, kg = (t & 3) * 16;
  short8v o0, o1;
#pragma unroll
  for (int j = 0; j < 8; ++j) o0[j] = (short)f2bf(tb[(kg + j) * 68 + dl]);
#pragma unroll
  for (int j = 0; j < 8; ++j) o1[j] = (short)f2bf(tb[(kg + 8 + j) * 68 + dl]);
  ushort* dst = ET + (size_t)(db + dl) * KCL + kb + kg;
  *reinterpret_cast<short8v*>(dst) = o0;
  *reinterpret_cast<short8v*>(dst + 8) = o1;
}

// ================= inproj32 (fp32, 32-row blocks, CIN split 2) =================
__global__ __launch_bounds__(256) void inproj32_kernel(const float* __restrict__ z,
                                                       const float* __restrict__ Wi,
                                                       const float* __restrict__ bi,
                                                       float* __restrict__ zd) {
  __shared__ float wi_s[32 * 260];
  __shared__ float zc[32 * 32];
  const int tid = threadIdx.x;
  const int nb = blockIdx.x >> 1, cih = blockIdx.x & 1;
  const int n0 = nb * 32;
  const int b = n0 / TSEQ;
  const int t0 = n0 % TSEQ;
  const float* zb = z + (size_t)b * CIN * TSEQ;
  const int ibase = cih * 512;

  const int dg = tid & 63;
  const int d0 = dg * 4;
  const int wv = tid >> 6;
  const int r0 = wv * 8;

  float acc[4][8];
#pragma unroll
  for (int c = 0; c < 4; ++c)
#pragma unroll
    for (int r = 0; r < 8; ++r) acc[c][r] = 0.f;

  for (int i0 = ibase; i0 < ibase + 512; i0 += 32) {
    __syncthreads();
    {
      const int iiq = (tid & 7) * 4;
      const int dt = tid >> 3;
#pragma unroll
      for (int p = 0; p < 8; ++p) {
        const int d = dt + p * 32;
        const float4 w = *reinterpret_cast<const float4*>(Wi + (size_t)d * CIN + i0 + iiq);
        wi_s[(iiq + 0) * 260 + d] = w.x;
        wi_s[(iiq + 1) * 260 + d] = w.y;
        wi_s[(iiq + 2) * 260 + d] = w.z;
        wi_s[(iiq + 3) * 260 + d] = w.w;
      }
      const int rr = tid & 31;
      const int iib = tid >> 5;
#pragma unroll
      for (int p = 0; p < 4; ++p) {
        const int ii = iib + p * 8;
        zc[ii * 32 + rr] = zb[(size_t)(i0 + ii) * TSEQ + t0 + rr];
      }
    }
    __syncthreads();
#pragma unroll
    for (int ii = 0; ii < 32; ++ii) {
      const float4 w = *reinterpret_cast<const float4*>(&wi_s[ii * 260 + d0]);
#pragma unroll
      for (int rq = 0; rq < 2; ++rq) {
        const float4 zv = *reinterpret_cast<const float4*>(&zc[ii * 32 + r0 + rq * 4]);
        const float zz[4] = {zv.x, zv.y, zv.z, zv.w};
#pragma unroll
        for (int q = 0; q < 4; ++q) {
          acc[0][rq * 4 + q] += w.x * zz[q];
          acc[1][rq * 4 + q] += w.y * zz[q];
          acc[2][rq * 4 + q] += w.z * zz[q];
          acc[3][rq * 4 + q] += w.w * zz[q];
        }
      }
    }
  }
  const float4 bv = *reinterpret_cast<const float4*>(bi + d0);
  const float bx = cih ? 0.f : bv.x, by = cih ? 0.f : bv.y;
  const float bz = cih ? 0.f : bv.z, bw = cih ? 0.f : bv.w;
#pragma unroll
  for (int r = 0; r < 8; ++r) {
    float* zr = zd + (size_t)(n0 + r0 + r) * DDIM + d0;
    atomicAdd(zr + 0, acc[0][r] + bx);
    atomicAdd(zr + 1, acc[1][r] + by);
    atomicAdd(zr + 2, acc[2][r] + bz);
    atomicAdd(zr + 3, acc[3][r] + bw);
  }
}

// ================= flashS: swapped QK MFMA + gumbel + P store + row stats ====
// grid 512 = nb(32) x kq(16) via XCD swizzle; block 512 = 8 waves.
// Output S^T: lane col = n (fixed row of P per lane), regs = 16 kcl.
#define FSS(KT, CUR, UC, UN)                                                   \
  {                                                                            \
    const int k0 = kbase + (KT) * 32;                                          \
    __syncthreads(); /* Es[CUR] staged + UC landed (drained here) */           \
    if ((KT) < 15) {                                                           \
      _Pragma("unroll")                                                        \
      for (int pp = 0; pp < 2; ++pp) {                                         \
        const int q = tid + pp * 512, r = q >> 5, c = q & 31;                  \
        gload16(Eb + (size_t)(k0 + 32 + r) * 256 + (size_t)(c ^ (r & 7)) * 8,  \
                &Es[(1 - (CUR)) * 8192 + q * 8]);                              \
      }                                                                        \
      const float* ubn = ubase + k0 + 32 + 4 * half;                           \
      _Pragma("unroll")                                                        \
      for (int q = 0; q < 4; ++q)                                              \
        UN[q] = *reinterpret_cast<const float4*>(ubn + q * 8);                 \
    }                                                                          \
    const ushort* Ecur = Es + (CUR) * 8192;                                    \
    f32x16 acc;                                                                \
    _Pragma("unroll")                                                          \
    for (int i = 0; i < 16; ++i) acc[i] = 0.f;                                 \
    _Pragma("unroll")                                                          \
    for (int ks = 0; ks < 16; ++ks) {                                          \
      const int cc = (ks * 2 + half) ^ (r31 & 7);                              \
      const short8v Af =                                                       \
          *reinterpret_cast<const short8v*>(Ecur + r31 * 256 + cc * 8);        \
      acc = __builtin_amdgcn_mfma_f32_32x32x16_bf16(Af, ZB[ks], acc, 0, 0, 0); \
    }                                                                          \
    ushort* pdst = P + (size_t)n * KCL + k0 + 4 * half;                        \
    _Pragma("unroll")                                                          \
    for (int q = 0; q < 4; ++q) {                                              \
      const float uu[4] = {UC[q].x, UC[q].y, UC[q].z, UC[q].w};                \
      short4v st;                                                              \
      _Pragma("unroll")                                                        \
      for (int j = 0; j < 4; ++j) {                                            \
        const int reg = q * 4 + j;                                             \
        const int kcl = k0 + q * 8 + 4 * half + j;                             \
        const float ce = c2s[kcl - kbase];                                     \
        const float D = 1e-10f - __logf(uu[j] + 1e-10f);                       \
        const float pe = __fdividef(__expf(fmaf(acc[reg], 2.f, ce)), D);       \
        psum += pe;                                                            \
        const bool cA = pe > b0v, cB = pe > b1v;                               \
        const float nv = cA ? b0v : pe; const int ni = cA ? b0i : kcl;         \
        b1v = cB ? nv : b1v; b1i = cB ? ni : b1i;                              \
        b0v = cA ? pe : b0v; b0i = cA ? kcl : b0i;                             \
        st[j] = (short)f2bf(pe);                                               \
      }                                                                        \
      *reinterpret_cast<short4v*>(pdst + q * 8) = st;                          \
    }                                                                          \
  }

__global__ __launch_bounds__(512, 2) void flashS_kernel(
    const ushort* __restrict__ ZDB, const float* __restrict__ u,
    const ushort* __restrict__ Eb, const float* __restrict__ c2,
    ushort* __restrict__ P, float* __restrict__ lsp,
    float* __restrict__ candv, int* __restrict__ candi) {
  __shared__ ushort Es[2 * 32 * 256];   // dbuf [32 kcl][256 d], swizzled, 32KB
  __shared__ float c2s[512];
  const int tid = threadIdx.x;
  const int l = tid & 63, w = tid >> 6;
  const int half = l >> 5;
  const int swz = (blockIdx.x & 7) * 64 + (blockIdx.x >> 3);
  const int nb = swz & 31, kq = swz >> 5;
  const int n0 = nb * 256;
  const int kbase = kq * 512;
  const int r31 = l & 31;
  const int n = n0 + w * 32 + r31;     // lane's P row (fixed)

  // B-frags: z row n, 16 frags of 8 bf16 (d = ks*16 + half*8 ..)
  short8v ZB[16];
  {
    const ushort* zr = ZDB + (size_t)n * DDIM + half * 8;
#pragma unroll
    for (int ks = 0; ks < 16; ++ks)
      ZB[ks] = *reinterpret_cast<const short8v*>(zr + ks * 16);
  }

  const float* ubase = u + ((size_t)n << 13);
  c2s[tid] = c2[kbase + tid];

  // prologue: stage kt=0 into buf 0, load u for kt=0
#pragma unroll
  for (int pp = 0; pp < 2; ++pp) {
    const int q = tid + pp * 512, r = q >> 5, c = q & 31;
    gload16(Eb + (size_t)(kbase + r) * 256 + (size_t)(c ^ (r & 7)) * 8, &Es[q * 8]);
  }
  float4 uA[4], uB[4];
  {
    const float* ub = ubase + kbase + 4 * half;
#pragma unroll
    for (int q = 0; q < 4; ++q)
      uA[q] = *reinterpret_cast<const float4*>(ub + q * 8);
  }

  float psum = 0.f;
  float b0v = -1.f, b1v = -1.f;
  int b0i = 0x7fffffff, b1i = 0x7fffffff;

  for (int kt2 = 0; kt2 < 16; kt2 += 2) {
    FSS(kt2, 0, uA, uB);
    FSS(kt2 + 1, 1, uB, uA);
  }

  // pair merge (l ^ 32): full 512-col stats for row n
  psum += __shfl_xor(psum, 32);
  {
    const float ov0 = __shfl_xor(b0v, 32); const int oi0 = __shfl_xor(b0i, 32);
    const float ov1 = __shfl_xor(b1v, 32); const int oi1 = __shfl_xor(b1i, 32);
    {
      const bool cA = (ov0 > b0v) || (ov0 == b0v && oi0 < b0i);
      const bool cB = (ov0 > b1v) || (ov0 == b1v && oi0 < b1i);
      const float nv = cA ? b0v : ov0; const int ni = cA ? b0i : oi0;
      b1v = cB ? nv : b1v; b1i = cB ? ni : b1i;
      b0v = cA ? ov0 : b0v; b0i = cA ? oi0 : b0i;
    }
    {
      const bool cA = (ov1 > b0v) || (ov1 == b0v && oi1 < b0i);
      const bool cB = (ov1 > b1v) || (ov1 == b1v && oi1 < b1i);
      const float nv = cA ? b0v : ov1; const int ni = cA ? b0i : oi1;
      b1v = cB ? nv : b1v; b1i = cB ? ni : b1i;
      b0v = cA ? ov1 : b0v; b0i = cA ? oi1 : b0i;
    }
  }
  if (half == 0) {
    lsp[kq * NROWS + n] = psum;
    candv[(kq * 2 + 0) * NROWS + n] = b0v;
    candi[(kq * 2 + 0) * NROWS + n] = b0i;
    candv[(kq * 2 + 1) * NROWS + n] = b1v;
    candi[(kq * 2 + 1) * NROWS + n] = b1i;
  }
}

// ================= rowfin: merge candidates + lsum + exact argmax =============
__global__ __launch_bounds__(256) void rowfin_kernel(
    const float* __restrict__ lsp, const float* __restrict__ candv,
    const int* __restrict__ candi, const float* __restrict__ zd,
    const float* __restrict__ E, const float* __restrict__ e2,
    const float* __restrict__ u, float* __restrict__ linv,
    float* __restrict__ counts) {
  const int l = threadIdx.x & 63;
  const int w = threadIdx.x >> 6;
  const int n = blockIdx.x * 4 + w;

  float bv[4] = {-1.f, -1.f, -1.f, -1.f};
  int bi[4] = {0x7fffffff, 0x7fffffff, 0x7fffffff, 0x7fffffff};
  if (l < 32) { bv[0] = candv[l * NROWS + n]; bi[0] = candi[l * NROWS + n]; }
#pragma unroll
  for (int mk = 1; mk < 64; mk <<= 1) {
    float ov[4]; int oi[4];
#pragma unroll
    for (int i = 0; i < 4; ++i) { ov[i] = __shfl_xor(bv[i], mk); oi[i] = __shfl_xor(bi[i], mk); }
#pragma unroll
    for (int i = 0; i < 4; ++i) {
      const float f = ov[i]; const int kk = oi[i];
      const bool c0 = (f > bv[0]) || (f == bv[0] && kk < bi[0]);
      const bool c1 = (f > bv[1]) || (f == bv[1] && kk < bi[1]);
      const bool c2 = (f > bv[2]) || (f == bv[2] && kk < bi[2]);
      const bool c3 = (f > bv[3]) || (f == bv[3] && kk < bi[3]);
      const float n3 = c2 ? bv[2] : f; const int i3 = c2 ? bi[2] : kk;
      const float n2 = c1 ? bv[1] : f; const int i2 = c1 ? bi[1] : kk;
      const float n1 = c0 ? bv[0] : f; const int i1 = c0 ? bi[0] : kk;
      bv[3] = c3 ? n3 : bv[3]; bi[3] = c3 ? i3 : bi[3];
      bv[2] = c2 ? n2 : bv[2]; bi[2] = c2 ? i2 : bi[2];
      bv[1] = c1 ? n1 : bv[1]; bi[1] = c1 ? i1 : bi[1];
      bv[0] = c0 ? f : bv[0];  bi[0] = c0 ? kk : bi[0];
    }
  }
  // lsum: fixed-pattern tree over 16 partials (deterministic)
  float ls = (l < 16) ? lsp[l * NROWS + n] : 0.f;
#pragma unroll
  for (int mk = 1; mk <= 8; mk <<= 1) ls += __shfl_xor(ls, mk);
  // exact fp32 eval of 4 candidates
  const float4 zv = *reinterpret_cast<const float4*>(zd + (size_t)n * DDIM + l * 4);
  float best = -1e30f; int besti = 0x7fffffff;
#pragma unroll
  for (int c = 0; c < 4; ++c) {
    const int kc = bi[c];
    const float4 ev = *reinterpret_cast<const float4*>(E + (size_t)kc * DDIM + l * 4);
    float d = zv.x * ev.x + zv.y * ev.y + zv.z * ev.z + zv.w * ev.w;
#pragma unroll
    for (int mk = 1; mk < 64; mk <<= 1) d += __shfl_xor(d, mk);
    const float uu = u[(size_t)n * KCL + kc];
    const float D = 1e-10f - __logf(uu + 1e-10f);
    const float g = -__logf(D);
    const float lg = 2.f * d - e2[kc] + g;
    if (lg > best || (lg == best && kc < besti)) { best = lg; besti = kc; }
  }
  if (l == 0) {
    atomicAdd(&counts[besti], 1.f);
    linv[n] = 1.f / ls;
  }
}

// ================= pvS: parts[ks] = p @ E, dbuf gload_lds P + global ET ======
// grid 512 = nb(128) x ks(4) via XCD swizzle; block 512 = 8 waves; wave 32n x 64d.
__global__ __launch_bounds__(512, 2) void pvS_kernel(
    const ushort* __restrict__ P, const ushort* __restrict__ ET,
    const float* __restrict__ linv, float* __restrict__ parts,
    float* __restrict__ colsum) {
  __shared__ ushort ps[2][64 * 64];  // dbuf 16KB, chunk-swizzled
  __shared__ float linv_s[64];
  const int tid = threadIdx.x;
  const int l = tid & 63, w = tid >> 6;
  const int half = l >> 5;
  const int r31 = l & 31;
  const int swz = (blockIdx.x & 7) * 64 + (blockIdx.x >> 3);
  const int nb = swz & 127, ks = swz >> 7;
  const int n0 = nb * 64;
  const int kc0 = ks * 2048;
  const int nw = w & 1, dw = w >> 1;
  const int sr = tid >> 3, sc = tid & 7;   // staging row/chunk (1 load/thread)

  if (tid < 64) linv_s[tid] = linv[n0 + tid];

  f32x16 acc0, acc1;
#pragma unroll
  for (int i = 0; i < 16; ++i) { acc0[i] = 0.f; acc1[i] = 0.f; }

  // prologue: stage tile 0 into buf 0 (swizzled source -> linear dest)
  gload16(P + (size_t)(n0 + sr) * KCL + kc0 + (size_t)(sc ^ (sr & 7)) * 8,
          &ps[0][tid * 8]);

  for (int t = 0; t < 32; ++t) {
    const int cur = t & 1;
    const int kc = kc0 + t * 64;
    __syncthreads();  // ps[cur] staged + everyone done with ps[cur^1]
    if (t < 31) {
      gload16(P + (size_t)(n0 + sr) * KCL + kc + 64 + (size_t)(sc ^ (sr & 7)) * 8,
              &ps[1 - cur][tid * 8]);
    }
#pragma unroll
    for (int ksn = 0; ksn < 4; ++ksn) {
      const int cc = ksn * 2 + half;
      short8v a, b0, b1;
      {
        const int r = nw * 32 + r31;
        a = *reinterpret_cast<const short8v*>(&ps[cur][r * 64 + ((cc ^ (r & 7))) * 8]);
      }
      {
        const ushort* etb = ET + (size_t)(dw * 64 + r31) * KCL + kc + cc * 8;
        b0 = *reinterpret_cast<const short8v*>(etb);
        b1 = *reinterpret_cast<const short8v*>(etb + (size_t)32 * KCL);
      }
      acc0 = __builtin_amdgcn_mfma_f32_32x32x16_bf16(a, b0, acc0, 0, 0, 0);
      acc1 = __builtin_amdgcn_mfma_f32_32x32x16_bf16(a, b1, acc1, 0, 0, 0);
    }
    // fused colsum partial for this 64x64 tile (ps[cur] valid till next barrier)
    {
      const int c = tid >> 3;
      const int rb = tid & 7;
      float csp = 0.f;
#pragma unroll
      for (int r8 = 0; r8 < 8; ++r8) {
        const int r = rb + r8 * 8;
        const int chunk = (c >> 3) ^ (r & 7);
        csp += bf2f(ps[cur][r * 64 + chunk * 8 + (c & 7)]) * linv_s[r];
      }
      csp += __shfl_xor(csp, 1);
      csp += __shfl_xor(csp, 2);
      csp += __shfl_xor(csp, 4);
      if (rb == 0) atomicAdd(&colsum[kc + c], csp);
    }
  }
  float* pbase = parts + (size_t)ks * NROWS * DDIM;
#pragma unroll
  for (int reg = 0; reg < 16; ++reg) {
    const int dr = (reg & 3) + 8 * (reg >> 2) + 4 * half;
    float* zr = pbase + (size_t)(n0 + nw * 32 + dr) * DDIM + dw * 64 + r31;
    zr[0]  = acc0[reg];
    zr[32] = acc1[reg];
  }
}

// ================= zqred: sum splits, scale by linv, write zq, vq partial =====
__global__ __launch_bounds__(256) void zqred_kernel(const float* __restrict__ parts,
                                                    const float* __restrict__ linv,
                                                    const float* __restrict__ zd,
                                                    float* __restrict__ zq,
                                                    float* __restrict__ vqs) {
  const size_t i = ((size_t)blockIdx.x * 256 + threadIdx.x) * 8;
  const int n = (int)(i >> 8);
  const float lv = linv[n];
  float s = 0.f;
#pragma unroll
  for (int j = 0; j < 8; j += 4) {
    float4 p0 = *reinterpret_cast<const float4*>(parts + i + j);
    const float4 p1 = *reinterpret_cast<const float4*>(parts + i + j + (size_t)NROWS * DDIM);
    const float4 p2 = *reinterpret_cast<const float4*>(parts + i + j + (size_t)2 * NROWS * DDIM);
    const float4 p3 = *reinterpret_cast<const float4*>(parts + i + j + (size_t)3 * NROWS * DDIM);
    const float4 a = *reinterpret_cast<const float4*>(zd + i + j);
    float4 o;
    o.x = (p0.x + p1.x + p2.x + p3.x) * lv;
    o.y = (p0.y + p1.y + p2.y + p3.y) * lv;
    o.z = (p0.z + p1.z + p2.z + p3.z) * lv;
    o.w = (p0.w + p1.w + p2.w + p3.w) * lv;
    *reinterpret_cast<float4*>(zq + i + j) = o;
    const float dx = a.x - o.x, dy = a.y - o.y, dz = a.z - o.z, dw = a.w - o.w;
    s += dx * dx + dy * dy + dz * dz + dw * dw;
  }
#pragma unroll
  for (int mk = 1; mk < 64; mk <<= 1) s += __shfl_xor(s, mk);
  if ((threadIdx.x & 63) == 0) atomicAdd(vqs, s);
}

// ================= outproj via MFMA =================
__global__ __launch_bounds__(256) void outproj2_kernel(const float* __restrict__ zq,
                                                       const ushort* __restrict__ Wob,
                                                       const float* __restrict__ bo,
                                                       float* __restrict__ outp) {
  extern __shared__ char smem[];
  ushort* zs = (ushort*)smem;
  ushort* wsld = zs + 64 * 256;
  const int tid = threadIdx.x;
  const int l = tid & 63, w = tid >> 6;
  const int half = l >> 5;
  const int nb = blockIdx.x >> 4, ob = blockIdx.x & 15;
  const int n0 = nb * 64, o0 = ob * 64;
  const int nw = w & 1, ow = w >> 1;
  {
    const int row = tid >> 2, seg = tid & 3;
    const float* zr = zq + (size_t)(n0 + row) * DDIM + seg * 64;
    const ushort* wr = Wob + (size_t)(o0 + row) * DDIM + seg * 64;
#pragma unroll
    for (int g = 0; g < 8; ++g) {
      const float4 a = *reinterpret_cast<const float4*>(zr + g * 8);
      const float4 b = *reinterpret_cast<const float4*>(zr + g * 8 + 4);
      const int c = seg * 8 + g;
      *reinterpret_cast<short8v*>(zs + row * 256 + ((c ^ (row & 7))) * 8) = pack8(a, b);
      const short8v wv = *reinterpret_cast<const short8v*>(wr + g * 8);
      *reinterpret_cast<short8v*>(wsld + row * 256 + ((c ^ (row & 7))) * 8) = wv;
    }
  }
  __syncthreads();
  f32x16 acc;
#pragma unroll
  for (int i = 0; i < 16; ++i) acc[i] = 0.f;
#pragma unroll
  for (int ksn = 0; ksn < 16; ++ksn) {
    const int cc = ksn * 2 + half;
    const int ra = nw * 32 + (l & 31);
    const int rb = ow * 32 + (l & 31);
    const short8v a = *reinterpret_cast<const short8v*>(zs + ra * 256 + ((cc ^ (ra & 7))) * 8);
    const short8v b = *reinterpret_cast<const short8v*>(wsld + rb * 256 + ((cc ^ (rb & 7))) * 8);
    acc = __builtin_amdgcn_mfma_f32_32x32x16_bf16(a, b, acc, 0, 0, 0);
  }
  const int o = o0 + ow * 32 + (l & 31);
  const float bvv = bo[o];
  const int nbase = n0 + nw * 32 + 4 * half;
#pragma unroll
  for (int rq = 0; rq < 4; ++rq) {
    const int n = nbase + rq * 8;
    const int b = n >> 11;
    const int tt = n & 2047;
    float4 ov;
    ov.x = acc[rq * 4 + 0] + bvv;
    ov.y = acc[rq * 4 + 1] + bvv;
    ov.z = acc[rq * 4 + 2] + bvv;
    ov.w = acc[rq * 4 + 3] + bvv;
    *reinterpret_cast<float4*>(outp + ((size_t)b * CIN + o) * TSEQ + tt) = ov;
  }
}

// ================= round-1 fallback flash (fp32) =================
template <bool STORE_LG>
__global__ __launch_bounds__(512) void flash_kernel(
    const float* __restrict__ zd, const float* __restrict__ u,
    const float* __restrict__ E, const float* __restrict__ e2g,
    float* __restrict__ zq, float* __restrict__ colsum,
    float* __restrict__ counts, float* __restrict__ vqsum,
    float* __restrict__ linvg, __half* __restrict__ lgbuf) {
  extern __shared__ float lds[];
  float* zs = lds;
  float* es = zs + 32 * 260;
  float* e2t = es + 64 * 260;
  float* cst = e2t + 64;
  float* red = cst + 64;

  const int tid = threadIdx.x;
  const int lane = tid & 63;
  const int wv = tid >> 6;
  const int r = (lane >> 4) & 3;
  const int kg = lane & 15;
  const int row = wv * 4 + r;
  const int n0 = blockIdx.x * 32;
  const int n = n0 + row;

  {
    const int rr = tid >> 4;
    const int iq = tid & 15;
#pragma unroll
    for (int p = 0; p < 4; ++p) {
      const int i = iq * 16 + p * 4;
      *reinterpret_cast<float4*>(&zs[rr * 260 + i]) =
          *reinterpret_cast<const float4*>(zd + (size_t)(n0 + rr) * DDIM + i);
    }
  }

  float4 accp[4];
#pragma unroll
  for (int s = 0; s < 4; ++s) accp[s] = make_float4(0.f, 0.f, 0.f, 0.f);
  float lsum = 0.f;
  float best = -1e30f;
  int bidx = 0;

  const float* zrow = zs + row * 260;

  for (int t = 0; t < KCL / 64; ++t) {
    const int k0 = t * 64;
    __syncthreads();
    {
      const int iq = tid & 15;
#pragma unroll
      for (int pp = 0; pp < 2; ++pp) {
        const int kk = (tid >> 4) + pp * 32;
#pragma unroll
        for (int p = 0; p < 4; ++p) {
          const int i = iq * 16 + p * 4;
          *reinterpret_cast<float4*>(&es[kk * 260 + i]) =
              *reinterpret_cast<const float4*>(E + (size_t)(k0 + kk) * DDIM + i);
        }
      }
      if (tid < 64) e2t[tid] = e2g[k0 + tid];
    }
    __syncthreads();

    float acc4[4] = {0.f, 0.f, 0.f, 0.f};
#pragma unroll 4
    for (int i = 0; i < DDIM; i += 4) {
      const float4 zv = *reinterpret_cast<const float4*>(zrow + i);
#pragma unroll
      for (int jj = 0; jj < 4; ++jj) {
        const float4 ev = *reinterpret_cast<const float4*>(&es[(kg + jj * 16) * 260 + i]);
        acc4[jj] += zv.x * ev.x + zv.y * ev.y + zv.z * ev.z + zv.w * ev.w;
      }
    }

    float p4[4];
    float tmax = -1e30f;
    int tidx = 0;
#pragma unroll
    for (int jj = 0; jj < 4; ++jj) {
      const int kk = kg + jj * 16;
      const float uu = u[(size_t)n * KCL + k0 + kk];
      const float g = -__logf(-__logf(uu + EPSL) + EPSL);
      const float lt = 2.f * acc4[jj] - e2t[kk] + g - MHAT;
      const float pe = __expf(lt);
      p4[jj] = pe;
      lsum += pe;
      if (lt > tmax) { tmax = lt; tidx = k0 + kk; }
    }
#pragma unroll
    for (int mk = 1; mk <= 8; mk <<= 1) {
      const float ov = __shfl_xor(tmax, mk);
      const int oi = __shfl_xor(tidx, mk);
      if (ov > tmax || (ov == tmax && oi < tidx)) { tmax = ov; tidx = oi; }
    }
    if (tmax > best) { best = tmax; bidx = tidx; }

#pragma unroll
    for (int jj = 0; jj < 4; ++jj) {
#pragma unroll 4
      for (int q = 0; q < 16; ++q) {
        const int kk = jj * 16 + q;
        const float yv = __shfl(p4[jj], (lane & 48) | q);
        const float* erow = &es[kk * 260 + kg * 16];
#pragma unroll
        for (int s = 0; s < 4; ++s) {
          const int c = (s + kg) & 3;
          const float4 ev = *reinterpret_cast<const float4*>(erow + c * 4);
          accp[s].x += yv * ev.x;
          accp[s].y += yv * ev.y;
          accp[s].z += yv * ev.z;
          accp[s].w += yv * ev.w;
        }
      }
    }
  }

#pragma unroll
  for (int mk = 1; mk <= 8; mk <<= 1) lsum += __shfl_xor(lsum, mk);
  const float linv = 1.0f / lsum;

  if (kg == 0) {
    atomicAdd(&counts[bidx], 1.0f);
    linvg[n] = linv;
  }

  float vqp = 0.f;
#pragma unroll
  for (int s = 0; s < 4; ++s) {
    const int c = (s + kg) & 3;
    const int d = kg * 16 + c * 4;
    float4 o;
    o.x = accp[s].x * linv;
    o.y = accp[s].y * linv;
    o.z = accp[s].z * linv;
    o.w = accp[s].w * linv;
    *reinterpret_cast<float4*>(zq + (size_t)n * DDIM + d) = o;
    const float4 zv = *reinterpret_cast<const float4*>(zrow + d);
    const float dx = zv.x - o.x, dy = zv.y - o.y, dz = zv.z - o.z, dw = zv.w - o.w;
    vqp += dx * dx + dy * dy + dz * dz + dw * dw;
  }
#pragma unroll
  for (int mk = 1; mk <= 32; mk <<= 1) vqp += __shfl_xor(vqp, mk);
  if (lane == 0) red[wv] = vqp;
  __syncthreads();
  if (tid == 0) {
    float s = 0.f;
#pragma unroll
    for (int ww = 0; ww < 8; ++ww) s += red[ww];
    atomicAdd(vqsum, s);
  }

  if (!STORE_LG) {
    if (tid < 64) cst[tid] = 0.f;
    for (int t = 0; t < KCL / 64; ++t) {
      const int k0 = t * 64;
      __syncthreads();
      {
        const int iq = tid & 15;
#pragma unroll
        for (int pp = 0; pp < 2; ++pp) {
          const int kk = (tid >> 4) + pp * 32;
#pragma unroll
          for (int p = 0; p < 4; ++p) {
            const int i = iq * 16 + p * 4;
            *reinterpret_cast<float4*>(&es[kk * 260 + i]) =
                *reinterpret_cast<const float4*>(E + (size_t)(k0 + kk) * DDIM + i);
          }
        }
        if (tid < 64) e2t[tid] = e2g[k0 + tid];
      }
      __syncthreads();
      float acc4[4] = {0.f, 0.f, 0.f, 0.f};
#pragma unroll 4
      for (int i = 0; i < DDIM; i += 4) {
        const float4 zv = *reinterpret_cast<const float4*>(zrow + i);
#pragma unroll
        for (int jj = 0; jj < 4; ++jj) {
          const float4 ev = *reinterpret_cast<const float4*>(&es[(kg + jj * 16) * 260 + i]);
          acc4[jj] += zv.x * ev.x + zv.y * ev.y + zv.z * ev.z + zv.w * ev.w;
        }
      }
      float cs4[4];
#pragma unroll
      for (int jj = 0; jj < 4; ++jj) {
        const int kk = kg + jj * 16;
        const float uu = u[(size_t)n * KCL + k0 + kk];
        const float g = -__logf(-__logf(uu + EPSL) + EPSL);
        const float lt = 2.f * acc4[jj] - e2t[kk] + g - MHAT;
        cs4[jj] = __expf(lt) * linv;
      }
#pragma unroll
      for (int mk = 16; mk <= 32; mk <<= 1)
#pragma unroll
        for (int jj = 0; jj < 4; ++jj) cs4[jj] += __shfl_xor(cs4[jj], mk);
      if (lane < 16) {
#pragma unroll
        for (int jj = 0; jj < 4; ++jj) atomicAdd(&cst[kg + jj * 16], cs4[jj]);
      }
      __syncthreads();
      if (tid < 64) {
        atomicAdd(&colsum[k0 + tid], cst[tid]);
        cst[tid] = 0.f;
      }
    }
  }
}

// ================= round-1 outproj (fp32, fallback) =================
__global__ __launch_bounds__(256) void outproj_kernel(const float* __restrict__ zq,
                                                      const float* __restrict__ Wo,
                                                      const float* __restrict__ bo,
                                                      float* __restrict__ outp) {
  __shared__ float wo_s[32 * 260];
  __shared__ float zc[32 * 68];
  const int tid = threadIdx.x;
  const int n0 = (blockIdx.x >> 2) * 64;
  const int ot = (blockIdx.x & 3) * 256;
  const int b = n0 / TSEQ;
  const int t0 = n0 % TSEQ;

  const int og = tid & 63;
  const int o0 = og * 4;
  const int wv = tid >> 6;
  const int r0 = wv * 16;

  float acc[4][16];
#pragma unroll
  for (int c = 0; c < 4; ++c)
#pragma unroll
    for (int r = 0; r < 16; ++r) acc[c][r] = 0.f;

  for (int dd = 0; dd < DDIM; dd += 32) {
    __syncthreads();
    {
      const int ccq = (tid & 7) * 4;
      const int oq = tid >> 3;
#pragma unroll
      for (int p = 0; p < 8; ++p) {
        const int oo = oq + p * 32;
        const float4 w = *reinterpret_cast<const float4*>(Wo + (size_t)(ot + oo) * DDIM + dd + ccq);
        wo_s[(ccq + 0) * 260 + oo] = w.x;
        wo_s[(ccq + 1) * 260 + oo] = w.y;
        wo_s[(ccq + 2) * 260 + oo] = w.z;
        wo_s[(ccq + 3) * 260 + oo] = w.w;
      }
#pragma unroll
      for (int p = 0; p < 2; ++p) {
        const int rr = oq + p * 32;
        const float4 v = *reinterpret_cast<const float4*>(zq + (size_t)(n0 + rr) * DDIM + dd + ccq);
        zc[(ccq + 0) * 68 + rr] = v.x;
        zc[(ccq + 1) * 68 + rr] = v.y;
        zc[(ccq + 2) * 68 + rr] = v.z;
        zc[(ccq + 3) * 68 + rr] = v.w;
      }
    }
    __syncthreads();
#pragma unroll
    for (int cc = 0; cc < 32; ++cc) {
      const float4 w = *reinterpret_cast<const float4*>(&wo_s[cc * 260 + o0]);
#pragma unroll
      for (int rq = 0; rq < 4; ++rq) {
        const float4 zv = *reinterpret_cast<const float4*>(&zc[cc * 68 + r0 + rq * 4]);
        const float zz[4] = {zv.x, zv.y, zv.z, zv.w};
#pragma unroll
        for (int q = 0; q < 4; ++q) {
          acc[0][rq * 4 + q] += w.x * zz[q];
          acc[1][rq * 4 + q] += w.y * zz[q];
          acc[2][rq * 4 + q] += w.z * zz[q];
          acc[3][rq * 4 + q] += w.w * zz[q];
        }
      }
    }
  }
  const float4 bv = *reinterpret_cast<const float4*>(bo + ot + o0);
  float* ob = outp + (size_t)b * CIN * TSEQ + t0;
  const float bb[4] = {bv.x, bv.y, bv.z, bv.w};
#pragma unroll
  for (int c = 0; c < 4; ++c) {
#pragma unroll
    for (int rq = 0; rq < 4; ++rq) {
      float4 o;
      o.x = acc[c][rq * 4 + 0] + bb[c];
      o.y = acc[c][rq * 4 + 1] + bb[c];
      o.z = acc[c][rq * 4 + 2] + bb[c];
      o.w = acc[c][rq * 4 + 3] + bb[c];
      *reinterpret_cast<float4*>(ob + (size_t)(ot + o0 + c) * TSEQ + r0 + rq * 4) = o;
    }
  }
}

// ================= finalize (shared) =================
__global__ __launch_bounds__(256) void finalize_kernel(
    const float* __restrict__ colsum, const float* __restrict__ counts,
    const float* __restrict__ vqsum, const float* __restrict__ csin,
    float* __restrict__ outsc, float* __restrict__ ncs) {
  __shared__ float rS[3][4];
  const int tid = threadIdx.x;
  const int lane = tid & 63;
  const int wv = tid >> 6;
  float sLog = 0.f, sH = 0.f, sAct = 0.f;
  for (int k = tid; k < KCL; k += 256) {
    const float avg = colsum[k] * (1.0f / NROWS);
    sLog += __logf(avg + EPSL);
    const float pb = counts[k] * (1.0f / NROWS);
    sH += pb * __logf(pb + EPSL);
    sAct += (csin[k] > 2.0f) ? 1.f : 0.f;
    ncs[k] = csin[k] * 0.99f + counts[k] * 0.01f;
  }
#pragma unroll
  for (int mk = 1; mk <= 32; mk <<= 1) {
    sLog += __shfl_xor(sLog, mk);
    sH += __shfl_xor(sH, mk);
    sAct += __shfl_xor(sAct, mk);
  }
  if (lane == 0) { rS[0][wv] = sLog; rS[1][wv] = sH; rS[2][wv] = sAct; }
  __syncthreads();
  if (tid == 0) {
    float SL = 0.f, SH = 0.f, SA = 0.f;
#pragma unroll
    for (int w = 0; w < 4; ++w) { SL += rS[0][w]; SH += rS[1][w]; SA += rS[2][w]; }
    outsc[0] = vqsum[0] * (1.0f / ((float)NROWS * (float)DDIM));
    outsc[1] = (float)NROWS * __logf(1.0f / (float)KCL) - SL;
    outsc[2] = __expf(-SH);
    outsc[3] = SA;
  }
}

extern "C" void kernel_launch(void* const* d_in, const int* in_sizes, int n_in,
                              void* d_out, int out_size, void* d_ws, size_t ws_size,
                              hipStream_t stream) {
  (void)in_sizes; (void)n_in; (void)out_size;
  const float* z = (const float*)d_in[0];
  const float* u = (const float*)d_in[1];
  const float* Wi = (const float*)d_in[2];
  const float* bi = (const float*)d_in[3];
  const float* Wo = (const float*)d_in[4];
  const float* bo = (const float*)d_in[5];
  const float* E = (const float*)d_in[6];
  const float* csin = (const float*)d_in[7];
  float* outp = (float*)d_out;
  float* ws = (float*)d_ws;

  const size_t needNew = (size_t)ENDW * 4;
  if (ws_size >= needNew) {
    ushort* EB = (ushort*)(ws + EBW);
    ushort* ET = (ushort*)(ws + ETW);
    ushort* WOB = (ushort*)(ws + WOBW);
    ushort* ZDB = (ushort*)(ws + ZDBW);
    ushort* P = (ushort*)(ws + PW);

    hipMemsetAsync((void*)(ws + CSUMW), 0, (size_t)(2 * KCL + 64) * 4, stream);
    hipMemsetAsync((void*)(ws + ZD2W), 0, (size_t)NROWS * DDIM * 4, stream);

    e2c2_kernel<<<KCL / 64, 256, 0, stream>>>(E, ws + E2W, ws + C2W);
    etprep_kernel<<<512, 256, 0, stream>>>(E, ET, EB);
    cvtwob_kernel<<<128, 256, 0, stream>>>(Wo, WOB);
    inproj32_kernel<<<512, 256, 0, stream>>>(z, Wi, bi, ws + ZD2W);
    cvtwob_kernel<<<1024, 256, 0, stream>>>(ws + ZD2W, ZDB);  // zd -> bf16

    flashS_kernel<<<512, 512, 0, stream>>>(ZDB, u, EB, ws + C2W, P,
                                           ws + LSPW, ws + CVW, (int*)(ws + CIW));
    rowfin_kernel<<<NROWS / 4, 256, 0, stream>>>(ws + LSPW, ws + CVW,
                                                 (const int*)(ws + CIW),
                                                 ws + ZD2W, E, ws + E2W, u,
                                                 ws + LINVW, ws + CNTW);
    // split-K partials scribbled into d_out (exactly OUT_SC floats), then
    // reduced into zq; outproj2 overwrites d_out afterwards. colsum fused here.
    pvS_kernel<<<512, 512, 0, stream>>>(P, ET, ws + LINVW, outp, ws + CSUMW);
    zqred_kernel<<<1024, 256, 0, stream>>>(outp, ws + LINVW, ws + ZD2W,
                                           ws + ZQ2W, ws + VQW);

    hipFuncSetAttribute(reinterpret_cast<const void*>(&outproj2_kernel),
                        hipFuncAttributeMaxDynamicSharedMemorySize, 65536);
    outproj2_kernel<<<2048, 256, 65536, stream>>>(ws + ZQ2W, WOB, bo, outp);
    finalize_kernel<<<1, 256, 0, stream>>>(ws + CSUMW, ws + CNTW, ws + VQW,
                                           csin, outp + OUT_SC, outp + OUT_SC + 4);
  } else {
    hipMemsetAsync((void*)(ws + CS_OFF), 0, (size_t)(2 * KCL + 1) * sizeof(float), stream);
    hipMemsetAsync((void*)(ws + ZD_OFF), 0, (size_t)NROWS * DDIM * 4, stream);
    e2_kernel<<<KCL / 64, 256, 0, stream>>>(E, ws + E2_OFF);
    inproj32_kernel<<<512, 256, 0, stream>>>(z, Wi, bi, ws + ZD_OFF);
    const int ldsB = (32 * 260 + 64 * 260 + 64 + 64 + 16) * 4;
    hipFuncSetAttribute(reinterpret_cast<const void*>(&flash_kernel<false>),
                        hipFuncAttributeMaxDynamicSharedMemorySize, ldsB);
    flash_kernel<false><<<NROWS / 32, 512, ldsB, stream>>>(
        ws + ZD_OFF, u, E, ws + E2_OFF, ws + ZQ_OFF, ws + CS_OFF, ws + CNT_OFF,
        ws + VQ_OFF, ws + LINV_OFF, (__half*)nullptr);
    outproj_kernel<<<(NROWS / 64) * 4, 256, 0, stream>>>(ws + ZQ_OFF, Wo, bo, outp);
    finalize_kernel<<<1, 256, 0, stream>>>(ws + CS_OFF, ws + CNT_OFF, ws + VQ_OFF,
                                           csin, outp + OUT_SC, outp + OUT_SC + 4);
  }
}

// Round 11
// 489.206 us; speedup vs baseline: 1.2415x; 1.2401x over previous
//
#include <hip/hip_runtime.h>
#include <hip/hip_fp16.h>

// VectorQuantize forward, round 11:
// - flashS2: swapped-operand QK (lane owns ONE P row) with LDS-staged,
//   COALESCED P flush (fixes round-10's 1.8x write amplification: 8B/row
//   scattered stores -> 64B-line flush, flash4's proven store shape).
//   Lane-local row stats (lsum+top2) kept; rowpass eliminated.
// - pv2 reverted to round-7 exact (es LDS staging + fused colsum + XCD swz);
//   round-10's direct-global ET B-frags destroyed reuse.
// - rowfin, inproj32, zqred, outproj2, finalize, prep kernels unchanged.

#define NROWS 8192
#define KCL   8192
#define DDIM  256
#define CIN   1024
#define TSEQ  2048
#define EPSL  1e-10f
#define MHAT  (-140.0f)

#define OUT_SC   (4*CIN*TSEQ)   // 8388608 == 4 * NROWS * DDIM (split-K parts fit)

// ---- old-path (round-1 fallback) ws offsets ----
#define ZD_OFF   0
#define ZQ_OFF   (NROWS*DDIM)
#define E2_OFF   (2*NROWS*DDIM)
#define CS_OFF   (E2_OFF + KCL)
#define CNT_OFF  (CS_OFF + KCL)
#define VQ_OFF   (CNT_OFF + KCL)
#define LINV_OFF (VQ_OFF + 4)

// ---- new-path ws offsets (float words) ----
#define ZD2W   0
#define ZQ2W   2097152
#define EBW    4194304
#define ETW    5242880
#define WOBW   6291456
#define ZDBW   6422528          // bf16 zd [N][D]
#define E2W    7471104
#define C2W    7479296
#define LINVW  7487488
#define CSUMW  7495680
#define CNTW   7503872
#define VQW    7512064
#define PW     7512128
#define ENDW   (PW + 33554432)
// transient stats in the zq region (consumed by rowfin before zqred writes zq)
#define LSPW   ZQ2W
#define CVW    (ZQ2W + 131072)
#define CIW    (ZQ2W + 393216)

using short8v = __attribute__((ext_vector_type(8))) short;
using short4v = __attribute__((ext_vector_type(4))) short;
using f32x16  = __attribute__((ext_vector_type(16))) float;

__device__ __forceinline__ ushort f2bf(float f) {
  unsigned int x = __float_as_uint(f);
  return (ushort)((x + 0x7FFFu + ((x >> 16) & 1u)) >> 16);
}
__device__ __forceinline__ float bf2f(ushort h) {
  return __uint_as_float(((unsigned int)h) << 16);
}
__device__ __forceinline__ short8v pack8(float4 a, float4 b) {
  short8v v;
  v[0] = (short)f2bf(a.x); v[1] = (short)f2bf(a.y);
  v[2] = (short)f2bf(a.z); v[3] = (short)f2bf(a.w);
  v[4] = (short)f2bf(b.x); v[5] = (short)f2bf(b.y);
  v[6] = (short)f2bf(b.z); v[7] = (short)f2bf(b.w);
  return v;
}
__device__ __forceinline__ void gload16(const void* g, void* l) {
  __builtin_amdgcn_global_load_lds(
      (const __attribute__((address_space(1))) unsigned int*)g,
      (__attribute__((address_space(3))) unsigned int*)l, 16, 0, 0);
}

// ================= shared prep =================

__global__ __launch_bounds__(256) void e2_kernel(const float* __restrict__ E,
                                                 float* __restrict__ e2) {
  const int tid = threadIdx.x;
  const int k = blockIdx.x * 64 + (tid >> 2);
  const int p = tid & 3;
  const float* row = E + (size_t)k * DDIM + p * 64;
  float s = 0.f;
#pragma unroll
  for (int j = 0; j < 16; ++j) {
    const float4 v = *reinterpret_cast<const float4*>(row + j * 4);
    s += v.x * v.x + v.y * v.y + v.z * v.z + v.w * v.w;
  }
  s += __shfl_xor(s, 1);
  s += __shfl_xor(s, 2);
  if (p == 0) e2[k] = s;
}

__global__ __launch_bounds__(256) void e2c2_kernel(const float* __restrict__ E,
                                                   float* __restrict__ e2,
                                                   float* __restrict__ c2) {
  const int tid = threadIdx.x;
  const int k = blockIdx.x * 64 + (tid >> 2);
  const int p = tid & 3;
  const float* row = E + (size_t)k * DDIM + p * 64;
  float s = 0.f;
#pragma unroll
  for (int j = 0; j < 16; ++j) {
    const float4 v = *reinterpret_cast<const float4*>(row + j * 4);
    s += v.x * v.x + v.y * v.y + v.z * v.z + v.w * v.w;
  }
  s += __shfl_xor(s, 1);
  s += __shfl_xor(s, 2);
  if (p == 0) { e2[k] = s; c2[k] = -s - MHAT; }
}

// generic f32 -> bf16 cast (used for Wo and for zd -> ZDB)
__global__ __launch_bounds__(256) void cvtwob_kernel(const float* __restrict__ W,
                                                     ushort* __restrict__ Wb) {
  const size_t i = ((size_t)blockIdx.x * 256 + threadIdx.x) * 8;
  const float4 a = *reinterpret_cast<const float4*>(W + i);
  const float4 b = *reinterpret_cast<const float4*>(W + i + 4);
  *reinterpret_cast<short8v*>(Wb + i) = pack8(a, b);
}

// E [K][D] f32 -> ET [D][K] bf16 AND EB [K][D] bf16 (fused)
__global__ __launch_bounds__(256) void etprep_kernel(const float* __restrict__ E,
                                                     ushort* __restrict__ ET,
                                                     ushort* __restrict__ EB) {
  __shared__ float tb[64 * 68];
  const int t = threadIdx.x;
  const int kb = (blockIdx.x & 127) * 64;
  const int db = (blockIdx.x >> 7) * 64;
#pragma unroll
  for (int it = 0; it < 4; ++it) {
    const int r = (t >> 4) + it * 16;
    const int c = (t & 15) * 4;
    const float4 v = *reinterpret_cast<const float4*>(E + (size_t)(kb + r) * DDIM + db + c);
    tb[r * 68 + c] = v.x; tb[r * 68 + c + 1] = v.y;
    tb[r * 68 + c + 2] = v.z; tb[r * 68 + c + 3] = v.w;
    short4v o;
    o[0] = (short)f2bf(v.x); o[1] = (short)f2bf(v.y);
    o[2] = (short)f2bf(v.z); o[3] = (short)f2bf(v.w);
    *reinterpret_cast<short4v*>(EB + (size_t)(kb + r) * DDIM + db + c) = o;
  }
  __syncthreads();
  const int dl = t >> 2, kg = (t & 3) * 16;
  short8v o0, o1;
#pragma unroll
  for (int j = 0; j < 8; ++j) o0[j] = (short)f2bf(tb[(kg + j) * 68 + dl]);
#pragma unroll
  for (int j = 0; j < 8; ++j) o1[j] = (short)f2bf(tb[(kg + 8 + j) * 68 + dl]);
  ushort* dst = ET + (size_t)(db + dl) * KCL + kb + kg;
  *reinterpret_cast<short8v*>(dst) = o0;
  *reinterpret_cast<short8v*>(dst + 8) = o1;
}

// ================= inproj32 (fp32, 32-row blocks, CIN split 2) =================
__global__ __launch_bounds__(256) void inproj32_kernel(const float* __restrict__ z,
                                                       const float* __restrict__ Wi,
                                                       const float* __restrict__ bi,
                                                       float* __restrict__ zd) {
  __shared__ float wi_s[32 * 260];
  __shared__ float zc[32 * 32];
  const int tid = threadIdx.x;
  const int nb = blockIdx.x >> 1, cih = blockIdx.x & 1;
  const int n0 = nb * 32;
  const int b = n0 / TSEQ;
  const int t0 = n0 % TSEQ;
  const float* zb = z + (size_t)b * CIN * TSEQ;
  const int ibase = cih * 512;

  const int dg = tid & 63;
  const int d0 = dg * 4;
  const int wv = tid >> 6;
  const int r0 = wv * 8;

  float acc[4][8];
#pragma unroll
  for (int c = 0; c < 4; ++c)
#pragma unroll
    for (int r = 0; r < 8; ++r) acc[c][r] = 0.f;

  for (int i0 = ibase; i0 < ibase + 512; i0 += 32) {
    __syncthreads();
    {
      const int iiq = (tid & 7) * 4;
      const int dt = tid >> 3;
#pragma unroll
      for (int p = 0; p < 8; ++p) {
        const int d = dt + p * 32;
        const float4 w = *reinterpret_cast<const float4*>(Wi + (size_t)d * CIN + i0 + iiq);
        wi_s[(iiq + 0) * 260 + d] = w.x;
        wi_s[(iiq + 1) * 260 + d] = w.y;
        wi_s[(iiq + 2) * 260 + d] = w.z;
        wi_s[(iiq + 3) * 260 + d] = w.w;
      }
      const int rr = tid & 31;
      const int iib = tid >> 5;
#pragma unroll
      for (int p = 0; p < 4; ++p) {
        const int ii = iib + p * 8;
        zc[ii * 32 + rr] = zb[(size_t)(i0 + ii) * TSEQ + t0 + rr];
      }
    }
    __syncthreads();
#pragma unroll
    for (int ii = 0; ii < 32; ++ii) {
      const float4 w = *reinterpret_cast<const float4*>(&wi_s[ii * 260 + d0]);
#pragma unroll
      for (int rq = 0; rq < 2; ++rq) {
        const float4 zv = *reinterpret_cast<const float4*>(&zc[ii * 32 + r0 + rq * 4]);
        const float zz[4] = {zv.x, zv.y, zv.z, zv.w};
#pragma unroll
        for (int q = 0; q < 4; ++q) {
          acc[0][rq * 4 + q] += w.x * zz[q];
          acc[1][rq * 4 + q] += w.y * zz[q];
          acc[2][rq * 4 + q] += w.z * zz[q];
          acc[3][rq * 4 + q] += w.w * zz[q];
        }
      }
    }
  }
  const float4 bv = *reinterpret_cast<const float4*>(bi + d0);
  const float bx = cih ? 0.f : bv.x, by = cih ? 0.f : bv.y;
  const float bz = cih ? 0.f : bv.z, bw = cih ? 0.f : bv.w;
#pragma unroll
  for (int r = 0; r < 8; ++r) {
    float* zr = zd + (size_t)(n0 + r0 + r) * DDIM + d0;
    atomicAdd(zr + 0, acc[0][r] + bx);
    atomicAdd(zr + 1, acc[1][r] + by);
    atomicAdd(zr + 2, acc[2][r] + bz);
    atomicAdd(zr + 3, acc[3][r] + bw);
  }
}

// ================= flashS2: swapped QK MFMA + gumbel + staged P flush ========
// grid 512 = nb(32) x kq(16) via XCD swizzle; block 512 = 8 waves.
// Lane owns ONE P row n. Epilogue stages the wave's 32x32 tile in LDS
// (pad-40 rows), then flushes coalesced 16B x 2/lane = 64B lines per row.
#define FSS(KT, CUR, UC, UN)                                                   \
  {                                                                            \
    const int k0 = kbase + (KT) * 32;                                          \
    __syncthreads(); /* Es[CUR] staged + UC landed (drained here) */           \
    if ((KT) < 15) {                                                           \
      _Pragma("unroll")                                                        \
      for (int pp = 0; pp < 2; ++pp) {                                         \
        const int q = tid + pp * 512, r = q >> 5, c = q & 31;                  \
        gload16(Eb + (size_t)(k0 + 32 + r) * 256 + (size_t)(c ^ (r & 7)) * 8,  \
                &Es[(1 - (CUR)) * 8192 + q * 8]);                              \
      }                                                                        \
      const float* ubn = ubase + k0 + 32 + 4 * half;                           \
      _Pragma("unroll")                                                        \
      for (int q = 0; q < 4; ++q)                                              \
        UN[q] = *reinterpret_cast<const float4*>(ubn + q * 8);                 \
    }                                                                          \
    const ushort* Ecur = Es + (CUR) * 8192;                                    \
    f32x16 acc;                                                                \
    _Pragma("unroll")                                                          \
    for (int i = 0; i < 16; ++i) acc[i] = 0.f;                                 \
    _Pragma("unroll")                                                          \
    for (int ks = 0; ks < 16; ++ks) {                                          \
      const int cc = (ks * 2 + half) ^ (r31 & 7);                              \
      const short8v Af =                                                       \
          *reinterpret_cast<const short8v*>(Ecur + r31 * 256 + cc * 8);        \
      acc = __builtin_amdgcn_mfma_f32_32x32x16_bf16(Af, ZB[ks], acc, 0, 0, 0); \
    }                                                                          \
    ushort* psw = Ps + w * 1280 + r31 * 40 + 4 * half;                         \
    _Pragma("unroll")                                                          \
    for (int q = 0; q < 4; ++q) {                                              \
      const float uu[4] = {UC[q].x, UC[q].y, UC[q].z, UC[q].w};                \
      short4v st;                                                              \
      _Pragma("unroll")                                                        \
      for (int j = 0; j < 4; ++j) {                                            \
        const int reg = q * 4 + j;                                             \
        const int kcl = k0 + q * 8 + 4 * half + j;                             \
        const float ce = c2s[kcl - kbase];                                     \
        const float D = 1e-10f - __logf(uu[j] + 1e-10f);                       \
        const float pe = __fdividef(__expf(fmaf(acc[reg], 2.f, ce)), D);       \
        psum += pe;                                                            \
        const bool cA = pe > b0v, cB = pe > b1v;                               \
        const float nv = cA ? b0v : pe; const int ni = cA ? b0i : kcl;         \
        b1v = cB ? nv : b1v; b1i = cB ? ni : b1i;                              \
        b0v = cA ? pe : b0v; b0i = cA ? kcl : b0i;                             \
        st[j] = (short)f2bf(pe);                                               \
      }                                                                        \
      *reinterpret_cast<short4v*>(psw + q * 8) = st;                           \
    }                                                                          \
    asm volatile("s_waitcnt lgkmcnt(0)" ::: "memory");                         \
    __builtin_amdgcn_sched_barrier(0);                                         \
    {                                                                          \
      const int frow = l >> 1, fpart = l & 1;                                  \
      const ushort* src = Ps + w * 1280 + frow * 40 + fpart * 16;              \
      ushort* dst = P + (size_t)(n0 + w * 32 + frow) * KCL + k0 + fpart * 16;  \
      *reinterpret_cast<short8v*>(dst) = *reinterpret_cast<const short8v*>(src);\
      *reinterpret_cast<short8v*>(dst + 8) =                                   \
          *reinterpret_cast<const short8v*>(src + 8);                          \
    }                                                                          \
  }

__global__ __launch_bounds__(512, 2) void flashS2_kernel(
    const ushort* __restrict__ ZDB, const float* __restrict__ u,
    const ushort* __restrict__ Eb, const float* __restrict__ c2,
    ushort* __restrict__ P, float* __restrict__ lsp,
    float* __restrict__ candv, int* __restrict__ candi) {
  __shared__ ushort Es[2 * 32 * 256];   // dbuf [32 kcl][256 d], swizzled, 32KB
  __shared__ ushort Ps[8 * 32 * 40];    // per-wave P tile, pad-40, 20KB
  __shared__ float c2s[512];
  const int tid = threadIdx.x;
  const int l = tid & 63, w = tid >> 6;
  const int half = l >> 5;
  const int swz = (blockIdx.x & 7) * 64 + (blockIdx.x >> 3);
  const int nb = swz & 31, kq = swz >> 5;
  const int n0 = nb * 256;
  const int kbase = kq * 512;
  const int r31 = l & 31;
  const int n = n0 + w * 32 + r31;     // lane's P row (fixed)

  // B-frags: z row n, 16 frags of 8 bf16 (d = ks*16 + half*8 ..)
  short8v ZB[16];
  {
    const ushort* zr = ZDB + (size_t)n * DDIM + half * 8;
#pragma unroll
    for (int ks = 0; ks < 16; ++ks)
      ZB[ks] = *reinterpret_cast<const short8v*>(zr + ks * 16);
  }

  const float* ubase = u + ((size_t)n << 13);
  c2s[tid] = c2[kbase + tid];

  // prologue: stage kt=0 into buf 0, load u for kt=0
#pragma unroll
  for (int pp = 0; pp < 2; ++pp) {
    const int q = tid + pp * 512, r = q >> 5, c = q & 31;
    gload16(Eb + (size_t)(kbase + r) * 256 + (size_t)(c ^ (r & 7)) * 8, &Es[q * 8]);
  }
  float4 uA[4], uB[4];
  {
    const float* ub = ubase + kbase + 4 * half;
#pragma unroll
    for (int q = 0; q < 4; ++q)
      uA[q] = *reinterpret_cast<const float4*>(ub + q * 8);
  }

  float psum = 0.f;
  float b0v = -1.f, b1v = -1.f;
  int b0i = 0x7fffffff, b1i = 0x7fffffff;

  for (int kt2 = 0; kt2 < 16; kt2 += 2) {
    FSS(kt2, 0, uA, uB);
    FSS(kt2 + 1, 1, uB, uA);
  }

  // pair merge (l ^ 32): full 512-col stats for row n
  psum += __shfl_xor(psum, 32);
  {
    const float ov0 = __shfl_xor(b0v, 32); const int oi0 = __shfl_xor(b0i, 32);
    const float ov1 = __shfl_xor(b1v, 32); const int oi1 = __shfl_xor(b1i, 32);
    {
      const bool cA = (ov0 > b0v) || (ov0 == b0v && oi0 < b0i);
      const bool cB = (ov0 > b1v) || (ov0 == b1v && oi0 < b1i);
      const float nv = cA ? b0v : ov0; const int ni = cA ? b0i : oi0;
      b1v = cB ? nv : b1v; b1i = cB ? ni : b1i;
      b0v = cA ? ov0 : b0v; b0i = cA ? oi0 : b0i;
    }
    {
      const bool cA = (ov1 > b0v) || (ov1 == b0v && oi1 < b0i);
      const bool cB = (ov1 > b1v) || (ov1 == b1v && oi1 < b1i);
      const float nv = cA ? b0v : ov1; const int ni = cA ? b0i : oi1;
      b1v = cB ? nv : b1v; b1i = cB ? ni : b1i;
      b0v = cA ? ov1 : b0v; b0i = cA ? oi1 : b0i;
    }
  }
  if (half == 0) {
    lsp[kq * NROWS + n] = psum;
    candv[(kq * 2 + 0) * NROWS + n] = b0v;
    candi[(kq * 2 + 0) * NROWS + n] = b0i;
    candv[(kq * 2 + 1) * NROWS + n] = b1v;
    candi[(kq * 2 + 1) * NROWS + n] = b1i;
  }
}

// ================= rowfin: merge candidates + lsum + exact argmax =============
__global__ __launch_bounds__(256) void rowfin_kernel(
    const float* __restrict__ lsp, const float* __restrict__ candv,
    const int* __restrict__ candi, const float* __restrict__ zd,
    const float* __restrict__ E, const float* __restrict__ e2,
    const float* __restrict__ u, float* __restrict__ linv,
    float* __restrict__ counts) {
  const int l = threadIdx.x & 63;
  const int w = threadIdx.x >> 6;
  const int n = blockIdx.x * 4 + w;

  float bv[4] = {-1.f, -1.f, -1.f, -1.f};
  int bi[4] = {0x7fffffff, 0x7fffffff, 0x7fffffff, 0x7fffffff};
  if (l < 32) { bv[0] = candv[l * NROWS + n]; bi[0] = candi[l * NROWS + n]; }
#pragma unroll
  for (int mk = 1; mk < 64; mk <<= 1) {
    float ov[4]; int oi[4];
#pragma unroll
    for (int i = 0; i < 4; ++i) { ov[i] = __shfl_xor(bv[i], mk); oi[i] = __shfl_xor(bi[i], mk); }
#pragma unroll
    for (int i = 0; i < 4; ++i) {
      const float f = ov[i]; const int kk = oi[i];
      const bool c0 = (f > bv[0]) || (f == bv[0] && kk < bi[0]);
      const bool c1 = (f > bv[1]) || (f == bv[1] && kk < bi[1]);
      const bool c2 = (f > bv[2]) || (f == bv[2] && kk < bi[2]);
      const bool c3 = (f > bv[3]) || (f == bv[3] && kk < bi[3]);
      const float n3 = c2 ? bv[2] : f; const int i3 = c2 ? bi[2] : kk;
      const float n2 = c1 ? bv[1] : f; const int i2 = c1 ? bi[1] : kk;
      const float n1 = c0 ? bv[0] : f; const int i1 = c0 ? bi[0] : kk;
      bv[3] = c3 ? n3 : bv[3]; bi[3] = c3 ? i3 : bi[3];
      bv[2] = c2 ? n2 : bv[2]; bi[2] = c2 ? i2 : bi[2];
      bv[1] = c1 ? n1 : bv[1]; bi[1] = c1 ? i1 : bi[1];
      bv[0] = c0 ? f : bv[0];  bi[0] = c0 ? kk : bi[0];
    }
  }
  // lsum: fixed-pattern tree over 16 partials (deterministic)
  float ls = (l < 16) ? lsp[l * NROWS + n] : 0.f;
#pragma unroll
  for (int mk = 1; mk <= 8; mk <<= 1) ls += __shfl_xor(ls, mk);
  // exact fp32 eval of 4 candidates
  const float4 zv = *reinterpret_cast<const float4*>(zd + (size_t)n * DDIM + l * 4);
  float best = -1e30f; int besti = 0x7fffffff;
#pragma unroll
  for (int c = 0; c < 4; ++c) {
    const int kc = bi[c];
    const float4 ev = *reinterpret_cast<const float4*>(E + (size_t)kc * DDIM + l * 4);
    float d = zv.x * ev.x + zv.y * ev.y + zv.z * ev.z + zv.w * ev.w;
#pragma unroll
    for (int mk = 1; mk < 64; mk <<= 1) d += __shfl_xor(d, mk);
    const float uu = u[(size_t)n * KCL + kc];
    const float D = 1e-10f - __logf(uu + 1e-10f);
    const float g = -__logf(D);
    const float lg = 2.f * d - e2[kc] + g;
    if (lg > best || (lg == best && kc < besti)) { best = lg; besti = kc; }
  }
  if (l == 0) {
    atomicAdd(&counts[besti], 1.f);
    linv[n] = 1.f / ls;
  }
}

// ================= pv2: parts[ks] = p @ E + fused colsum (round-7 exact) ======
// grid 512 = nb(128) x ks(4) via XCD swizzle; block 512 = 8 waves; wave 32n x 64d
__global__ __launch_bounds__(512, 2) void pv2_kernel(
    const ushort* __restrict__ P, const ushort* __restrict__ ET,
    const float* __restrict__ linv, float* __restrict__ parts,
    float* __restrict__ colsum) {
  __shared__ ushort ps[64 * 64];    // 8KB
  __shared__ ushort es[256 * 64];   // 32KB
  __shared__ float linv_s[64];
  const int tid = threadIdx.x;
  const int l = tid & 63, w = tid >> 6;
  const int half = l >> 5;
  const int r31 = l & 31;
  const int swz = (blockIdx.x & 7) * 64 + (blockIdx.x >> 3);
  const int nb = swz & 127, ks = swz >> 7;
  const int n0 = nb * 64;
  const int kc0 = ks * 2048;
  const int nw = w & 1, dw = w >> 1;

  if (tid < 64) linv_s[tid] = linv[n0 + tid];

  f32x16 acc0, acc1;
#pragma unroll
  for (int i = 0; i < 16; ++i) { acc0[i] = 0.f; acc1[i] = 0.f; }

  short8v rp, re[4];
  {
    const int r = tid >> 3, c = tid & 7;
    rp = *reinterpret_cast<const short8v*>(P + (size_t)(n0 + r) * KCL + kc0 + c * 8);
#pragma unroll
    for (int pp = 0; pp < 4; ++pp) {
      const int q = tid * 4 + pp; const int rr = q >> 3, cc = q & 7;
      re[pp] = *reinterpret_cast<const short8v*>(ET + (size_t)rr * KCL + kc0 + cc * 8);
    }
  }
  for (int t = 0; t < 32; ++t) {
    {
      const int r = tid >> 3, c = tid & 7;
      *reinterpret_cast<short8v*>(ps + r * 64 + ((c ^ (r & 7))) * 8) = rp;
    }
#pragma unroll
    for (int pp = 0; pp < 4; ++pp) {
      const int q = tid * 4 + pp; const int rr = q >> 3, cc = q & 7;
      *reinterpret_cast<short8v*>(es + rr * 64 + ((cc ^ (rr & 7))) * 8) = re[pp];
    }
    __syncthreads();
    if (t < 31) {
      const int kc = kc0 + (t + 1) * 64;
      {
        const int r = tid >> 3, c = tid & 7;
        rp = *reinterpret_cast<const short8v*>(P + (size_t)(n0 + r) * KCL + kc + c * 8);
      }
#pragma unroll
      for (int pp = 0; pp < 4; ++pp) {
        const int q = tid * 4 + pp; const int rr = q >> 3, cc = q & 7;
        re[pp] = *reinterpret_cast<const short8v*>(ET + (size_t)rr * KCL + kc + cc * 8);
      }
    }
#pragma unroll
    for (int ksn = 0; ksn < 4; ++ksn) {
      const int cc = ksn * 2 + half;
      short8v a, b0, b1;
      { const int r = nw * 32 + r31;      a  = *reinterpret_cast<const short8v*>(ps + r * 64 + ((cc ^ (r & 7))) * 8); }
      { const int r = dw * 64 + r31;      b0 = *reinterpret_cast<const short8v*>(es + r * 64 + ((cc ^ (r & 7))) * 8); }
      { const int r = dw * 64 + 32 + r31; b1 = *reinterpret_cast<const short8v*>(es + r * 64 + ((cc ^ (r & 7))) * 8); }
      acc0 = __builtin_amdgcn_mfma_f32_32x32x16_bf16(a, b0, acc0, 0, 0, 0);
      acc1 = __builtin_amdgcn_mfma_f32_32x32x16_bf16(a, b1, acc1, 0, 0, 0);
    }
    // fused colsum partial for this 64x64 tile (ps valid until the barrier)
    {
      const int c = tid >> 3;
      const int rb = tid & 7;
      float csp = 0.f;
#pragma unroll
      for (int r8 = 0; r8 < 8; ++r8) {
        const int r = rb + r8 * 8;
        const int chunk = (c >> 3) ^ (r & 7);
        csp += bf2f(ps[r * 64 + chunk * 8 + (c & 7)]) * linv_s[r];
      }
      csp += __shfl_xor(csp, 1);
      csp += __shfl_xor(csp, 2);
      csp += __shfl_xor(csp, 4);
      if (rb == 0) atomicAdd(&colsum[kc0 + t * 64 + c], csp);
    }
    __syncthreads();
  }
  float* pbase = parts + (size_t)ks * NROWS * DDIM;
#pragma unroll
  for (int reg = 0; reg < 16; ++reg) {
    const int dr = (reg & 3) + 8 * (reg >> 2) + 4 * half;
    float* zr = pbase + (size_t)(n0 + nw * 32 + dr) * DDIM + dw * 64 + r31;
    zr[0]  = acc0[reg];
    zr[32] = acc1[reg];
  }
}

// ================= zqred: sum splits, scale by linv, write zq, vq partial =====
__global__ __launch_bounds__(256) void zqred_kernel(const float* __restrict__ parts,
                                                    const float* __restrict__ linv,
                                                    const float* __restrict__ zd,
                                                    float* __restrict__ zq,
                                                    float* __restrict__ vqs) {
  const size_t i = ((size_t)blockIdx.x * 256 + threadIdx.x) * 8;
  const int n = (int)(i >> 8);
  const float lv = linv[n];
  float s = 0.f;
#pragma unroll
  for (int j = 0; j < 8; j += 4) {
    float4 p0 = *reinterpret_cast<const float4*>(parts + i + j);
    const float4 p1 = *reinterpret_cast<const float4*>(parts + i + j + (size_t)NROWS * DDIM);
    const float4 p2 = *reinterpret_cast<const float4*>(parts + i + j + (size_t)2 * NROWS * DDIM);
    const float4 p3 = *reinterpret_cast<const float4*>(parts + i + j + (size_t)3 * NROWS * DDIM);
    const float4 a = *reinterpret_cast<const float4*>(zd + i + j);
    float4 o;
    o.x = (p0.x + p1.x + p2.x + p3.x) * lv;
    o.y = (p0.y + p1.y + p2.y + p3.y) * lv;
    o.z = (p0.z + p1.z + p2.z + p3.z) * lv;
    o.w = (p0.w + p1.w + p2.w + p3.w) * lv;
    *reinterpret_cast<float4*>(zq + i + j) = o;
    const float dx = a.x - o.x, dy = a.y - o.y, dz = a.z - o.z, dw = a.w - o.w;
    s += dx * dx + dy * dy + dz * dz + dw * dw;
  }
#pragma unroll
  for (int mk = 1; mk < 64; mk <<= 1) s += __shfl_xor(s, mk);
  if ((threadIdx.x & 63) == 0) atomicAdd(vqs, s);
}

// ================= outproj via MFMA =================
__global__ __launch_bounds__(256) void outproj2_kernel(const float* __restrict__ zq,
                                                       const ushort* __restrict__ Wob,
                                                       const float* __restrict__ bo,
                                                       float* __restrict__ outp) {
  extern __shared__ char smem[];
  ushort* zs = (ushort*)smem;
  ushort* wsld = zs + 64 * 256;
  const int tid = threadIdx.x;
  const int l = tid & 63, w = tid >> 6;
  const int half = l >> 5;
  const int nb = blockIdx.x >> 4, ob = blockIdx.x & 15;
  const int n0 = nb * 64, o0 = ob * 64;
  const int nw = w & 1, ow = w >> 1;
  {
    const int row = tid >> 2, seg = tid & 3;
    const float* zr = zq + (size_t)(n0 + row) * DDIM + seg * 64;
    const ushort* wr = Wob + (size_t)(o0 + row) * DDIM + seg * 64;
#pragma unroll
    for (int g = 0; g < 8; ++g) {
      const float4 a = *reinterpret_cast<const float4*>(zr + g * 8);
      const float4 b = *reinterpret_cast<const float4*>(zr + g * 8 + 4);
      const int c = seg * 8 + g;
      *reinterpret_cast<short8v*>(zs + row * 256 + ((c ^ (row & 7))) * 8) = pack8(a, b);
      const short8v wv = *reinterpret_cast<const short8v*>(wr + g * 8);
      *reinterpret_cast<short8v*>(wsld + row * 256 + ((c ^ (row & 7))) * 8) = wv;
    }
  }
  __syncthreads();
  f32x16 acc;
#pragma unroll
  for (int i = 0; i < 16; ++i) acc[i] = 0.f;
#pragma unroll
  for (int ksn = 0; ksn < 16; ++ksn) {
    const int cc = ksn * 2 + half;
    const int ra = nw * 32 + (l & 31);
    const int rb = ow * 32 + (l & 31);
    const short8v a = *reinterpret_cast<const short8v*>(zs + ra * 256 + ((cc ^ (ra & 7))) * 8);
    const short8v b = *reinterpret_cast<const short8v*>(wsld + rb * 256 + ((cc ^ (rb & 7))) * 8);
    acc = __builtin_amdgcn_mfma_f32_32x32x16_bf16(a, b, acc, 0, 0, 0);
  }
  const int o = o0 + ow * 32 + (l & 31);
  const float bvv = bo[o];
  const int nbase = n0 + nw * 32 + 4 * half;
#pragma unroll
  for (int rq = 0; rq < 4; ++rq) {
    const int n = nbase + rq * 8;
    const int b = n >> 11;
    const int tt = n & 2047;
    float4 ov;
    ov.x = acc[rq * 4 + 0] + bvv;
    ov.y = acc[rq * 4 + 1] + bvv;
    ov.z = acc[rq * 4 + 2] + bvv;
    ov.w = acc[rq * 4 + 3] + bvv;
    *reinterpret_cast<float4*>(outp + ((size_t)b * CIN + o) * TSEQ + tt) = ov;
  }
}

// ================= round-1 fallback flash (fp32) =================
template <bool STORE_LG>
__global__ __launch_bounds__(512) void flash_kernel(
    const float* __restrict__ zd, const float* __restrict__ u,
    const float* __restrict__ E, const float* __restrict__ e2g,
    float* __restrict__ zq, float* __restrict__ colsum,
    float* __restrict__ counts, float* __restrict__ vqsum,
    float* __restrict__ linvg, __half* __restrict__ lgbuf) {
  extern __shared__ float lds[];
  float* zs = lds;
  float* es = zs + 32 * 260;
  float* e2t = es + 64 * 260;
  float* cst = e2t + 64;
  float* red = cst + 64;

  const int tid = threadIdx.x;
  const int lane = tid & 63;
  const int wv = tid >> 6;
  const int r = (lane >> 4) & 3;
  const int kg = lane & 15;
  const int row = wv * 4 + r;
  const int n0 = blockIdx.x * 32;
  const int n = n0 + row;

  {
    const int rr = tid >> 4;
    const int iq = tid & 15;
#pragma unroll
    for (int p = 0; p < 4; ++p) {
      const int i = iq * 16 + p * 4;
      *reinterpret_cast<float4*>(&zs[rr * 260 + i]) =
          *reinterpret_cast<const float4*>(zd + (size_t)(n0 + rr) * DDIM + i);
    }
  }

  float4 accp[4];
#pragma unroll
  for (int s = 0; s < 4; ++s) accp[s] = make_float4(0.f, 0.f, 0.f, 0.f);
  float lsum = 0.f;
  float best = -1e30f;
  int bidx = 0;

  const float* zrow = zs + row * 260;

  for (int t = 0; t < KCL / 64; ++t) {
    const int k0 = t * 64;
    __syncthreads();
    {
      const int iq = tid & 15;
#pragma unroll
      for (int pp = 0; pp < 2; ++pp) {
        const int kk = (tid >> 4) + pp * 32;
#pragma unroll
        for (int p = 0; p < 4; ++p) {
          const int i = iq * 16 + p * 4;
          *reinterpret_cast<float4*>(&es[kk * 260 + i]) =
              *reinterpret_cast<const float4*>(E + (size_t)(k0 + kk) * DDIM + i);
        }
      }
      if (tid < 64) e2t[tid] = e2g[k0 + tid];
    }
    __syncthreads();

    float acc4[4] = {0.f, 0.f, 0.f, 0.f};
#pragma unroll 4
    for (int i = 0; i < DDIM; i += 4) {
      const float4 zv = *reinterpret_cast<const float4*>(zrow + i);
#pragma unroll
      for (int jj = 0; jj < 4; ++jj) {
        const float4 ev = *reinterpret_cast<const float4*>(&es[(kg + jj * 16) * 260 + i]);
        acc4[jj] += zv.x * ev.x + zv.y * ev.y + zv.z * ev.z + zv.w * ev.w;
      }
    }

    float p4[4];
    float tmax = -1e30f;
    int tidx = 0;
#pragma unroll
    for (int jj = 0; jj < 4; ++jj) {
      const int kk = kg + jj * 16;
      const float uu = u[(size_t)n * KCL + k0 + kk];
      const float g = -__logf(-__logf(uu + EPSL) + EPSL);
      const float lt = 2.f * acc4[jj] - e2t[kk] + g - MHAT;
      const float pe = __expf(lt);
      p4[jj] = pe;
      lsum += pe;
      if (lt > tmax) { tmax = lt; tidx = k0 + kk; }
    }
#pragma unroll
    for (int mk = 1; mk <= 8; mk <<= 1) {
      const float ov = __shfl_xor(tmax, mk);
      const int oi = __shfl_xor(tidx, mk);
      if (ov > tmax || (ov == tmax && oi < tidx)) { tmax = ov; tidx = oi; }
    }
    if (tmax > best) { best = tmax; bidx = tidx; }

#pragma unroll
    for (int jj = 0; jj < 4; ++jj) {
#pragma unroll 4
      for (int q = 0; q < 16; ++q) {
        const int kk = jj * 16 + q;
        const float yv = __shfl(p4[jj], (lane & 48) | q);
        const float* erow = &es[kk * 260 + kg * 16];
#pragma unroll
        for (int s = 0; s < 4; ++s) {
          const int c = (s + kg) & 3;
          const float4 ev = *reinterpret_cast<const float4*>(erow + c * 4);
          accp[s].x += yv * ev.x;
          accp[s].y += yv * ev.y;
          accp[s].z += yv * ev.z;
          accp[s].w += yv * ev.w;
        }
      }
    }
  }

#pragma unroll
  for (int mk = 1; mk <= 8; mk <<= 1) lsum += __shfl_xor(lsum, mk);
  const float linv = 1.0f / lsum;

  if (kg == 0) {
    atomicAdd(&counts[bidx], 1.0f);
    linvg[n] = linv;
  }

  float vqp = 0.f;
#pragma unroll
  for (int s = 0; s < 4; ++s) {
    const int c = (s + kg) & 3;
    const int d = kg * 16 + c * 4;
    float4 o;
    o.x = accp[s].x * linv;
    o.y = accp[s].y * linv;
    o.z = accp[s].z * linv;
    o.w = accp[s].w * linv;
    *reinterpret_cast<float4*>(zq + (size_t)n * DDIM + d) = o;
    const float4 zv = *reinterpret_cast<const float4*>(zrow + d);
    const float dx = zv.x - o.x, dy = zv.y - o.y, dz = zv.z - o.z, dw = zv.w - o.w;
    vqp += dx * dx + dy * dy + dz * dz + dw * dw;
  }
#pragma unroll
  for (int mk = 1; mk <= 32; mk <<= 1) vqp += __shfl_xor(vqp, mk);
  if (lane == 0) red[wv] = vqp;
  __syncthreads();
  if (tid == 0) {
    float s = 0.f;
#pragma unroll
    for (int ww = 0; ww < 8; ++ww) s += red[ww];
    atomicAdd(vqsum, s);
  }

  if (!STORE_LG) {
    if (tid < 64) cst[tid] = 0.f;
    for (int t = 0; t < KCL / 64; ++t) {
      const int k0 = t * 64;
      __syncthreads();
      {
        const int iq = tid & 15;
#pragma unroll
        for (int pp = 0; pp < 2; ++pp) {
          const int kk = (tid >> 4) + pp * 32;
#pragma unroll
          for (int p = 0; p < 4; ++p) {
            const int i = iq * 16 + p * 4;
            *reinterpret_cast<float4*>(&es[kk * 260 + i]) =
                *reinterpret_cast<const float4*>(E + (size_t)(k0 + kk) * DDIM + i);
          }
        }
        if (tid < 64) e2t[tid] = e2g[k0 + tid];
      }
      __syncthreads();
      float acc4[4] = {0.f, 0.f, 0.f, 0.f};
#pragma unroll 4
      for (int i = 0; i < DDIM; i += 4) {
        const float4 zv = *reinterpret_cast<const float4*>(zrow + i);
#pragma unroll
        for (int jj = 0; jj < 4; ++jj) {
          const float4 ev = *reinterpret_cast<const float4*>(&es[(kg + jj * 16) * 260 + i]);
          acc4[jj] += zv.x * ev.x + zv.y * ev.y + zv.z * ev.z + zv.w * ev.w;
        }
      }
      float cs4[4];
#pragma unroll
      for (int jj = 0; jj < 4; ++jj) {
        const int kk = kg + jj * 16;
        const float uu = u[(size_t)n * KCL + k0 + kk];
        const float g = -__logf(-__logf(uu + EPSL) + EPSL);
        const float lt = 2.f * acc4[jj] - e2t[kk] + g - MHAT;
        cs4[jj] = __expf(lt) * linv;
      }
#pragma unroll
      for (int mk = 16; mk <= 32; mk <<= 1)
#pragma unroll
        for (int jj = 0; jj < 4; ++jj) cs4[jj] += __shfl_xor(cs4[jj], mk);
      if (lane < 16) {
#pragma unroll
        for (int jj = 0; jj < 4; ++jj) atomicAdd(&cst[kg + jj * 16], cs4[jj]);
      }
      __syncthreads();
      if (tid < 64) {
        atomicAdd(&colsum[k0 + tid], cst[tid]);
        cst[tid] = 0.f;
      }
    }
  }
}

// ================= round-1 outproj (fp32, fallback) =================
__global__ __launch_bounds__(256) void outproj_kernel(const float* __restrict__ zq,
                                                      const float* __restrict__ Wo,
                                                      const float* __restrict__ bo,
                                                      float* __restrict__ outp) {
  __shared__ float wo_s[32 * 260];
  __shared__ float zc[32 * 68];
  const int tid = threadIdx.x;
  const int n0 = (blockIdx.x >> 2) * 64;
  const int ot = (blockIdx.x & 3) * 256;
  const int b = n0 / TSEQ;
  const int t0 = n0 % TSEQ;

  const int og = tid & 63;
  const int o0 = og * 4;
  const int wv = tid >> 6;
  const int r0 = wv * 16;

  float acc[4][16];
#pragma unroll
  for (int c = 0; c < 4; ++c)
#pragma unroll
    for (int r = 0; r < 16; ++r) acc[c][r] = 0.f;

  for (int dd = 0; dd < DDIM; dd += 32) {
    __syncthreads();
    {
      const int ccq = (tid & 7) * 4;
      const int oq = tid >> 3;
#pragma unroll
      for (int p = 0; p < 8; ++p) {
        const int oo = oq + p * 32;
        const float4 w = *reinterpret_cast<const float4*>(Wo + (size_t)(ot + oo) * DDIM + dd + ccq);
        wo_s[(ccq + 0) * 260 + oo] = w.x;
        wo_s[(ccq + 1) * 260 + oo] = w.y;
        wo_s[(ccq + 2) * 260 + oo] = w.z;
        wo_s[(ccq + 3) * 260 + oo] = w.w;
      }
#pragma unroll
      for (int p = 0; p < 2; ++p) {
        const int rr = oq + p * 32;
        const float4 v = *reinterpret_cast<const float4*>(zq + (size_t)(n0 + rr) * DDIM + dd + ccq);
        zc[(ccq + 0) * 68 + rr] = v.x;
        zc[(ccq + 1) * 68 + rr] = v.y;
        zc[(ccq + 2) * 68 + rr] = v.z;
        zc[(ccq + 3) * 68 + rr] = v.w;
      }
    }
    __syncthreads();
#pragma unroll
    for (int cc = 0; cc < 32; ++cc) {
      const float4 w = *reinterpret_cast<const float4*>(&wo_s[cc * 260 + o0]);
#pragma unroll
      for (int rq = 0; rq < 4; ++rq) {
        const float4 zv = *reinterpret_cast<const float4*>(&zc[cc * 68 + r0 + rq * 4]);
        const float zz[4] = {zv.x, zv.y, zv.z, zv.w};
#pragma unroll
        for (int q = 0; q < 4; ++q) {
          acc[0][rq * 4 + q] += w.x * zz[q];
          acc[1][rq * 4 + q] += w.y * zz[q];
          acc[2][rq * 4 + q] += w.z * zz[q];
          acc[3][rq * 4 + q] += w.w * zz[q];
        }
      }
    }
  }
  const float4 bv = *reinterpret_cast<const float4*>(bo + ot + o0);
  float* ob = outp + (size_t)b * CIN * TSEQ + t0;
  const float bb[4] = {bv.x, bv.y, bv.z, bv.w};
#pragma unroll
  for (int c = 0; c < 4; ++c) {
#pragma unroll
    for (int rq = 0; rq < 4; ++rq) {
      float4 o;
      o.x = acc[c][rq * 4 + 0] + bb[c];
      o.y = acc[c][rq * 4 + 1] + bb[c];
      o.z = acc[c][rq * 4 + 2] + bb[c];
      o.w = acc[c][rq * 4 + 3] + bb[c];
      *reinterpret_cast<float4*>(ob + (size_t)(ot + o0 + c) * TSEQ + r0 + rq * 4) = o;
    }
  }
}

// ================= finalize (shared) =================
__global__ __launch_bounds__(256) void finalize_kernel(
    const float* __restrict__ colsum, const float* __restrict__ counts,
    const float* __restrict__ vqsum, const float* __restrict__ csin,
    float* __restrict__ outsc, float* __restrict__ ncs) {
  __shared__ float rS[3][4];
  const int tid = threadIdx.x;
  const int lane = tid & 63;
  const int wv = tid >> 6;
  float sLog = 0.f, sH = 0.f, sAct = 0.f;
  for (int k = tid; k < KCL; k += 256) {
    const float avg = colsum[k] * (1.0f / NROWS);
    sLog += __logf(avg + EPSL);
    const float pb = counts[k] * (1.0f / NROWS);
    sH += pb * __logf(pb + EPSL);
    sAct += (csin[k] > 2.0f) ? 1.f : 0.f;
    ncs[k] = csin[k] * 0.99f + counts[k] * 0.01f;
  }
#pragma unroll
  for (int mk = 1; mk <= 32; mk <<= 1) {
    sLog += __shfl_xor(sLog, mk);
    sH += __shfl_xor(sH, mk);
    sAct += __shfl_xor(sAct, mk);
  }
  if (lane == 0) { rS[0][wv] = sLog; rS[1][wv] = sH; rS[2][wv] = sAct; }
  __syncthreads();
  if (tid == 0) {
    float SL = 0.f, SH = 0.f, SA = 0.f;
#pragma unroll
    for (int w = 0; w < 4; ++w) { SL += rS[0][w]; SH += rS[1][w]; SA += rS[2][w]; }
    outsc[0] = vqsum[0] * (1.0f / ((float)NROWS * (float)DDIM));
    outsc[1] = (float)NROWS * __logf(1.0f / (float)KCL) - SL;
    outsc[2] = __expf(-SH);
    outsc[3] = SA;
  }
}

extern "C" void kernel_launch(void* const* d_in, const int* in_sizes, int n_in,
                              void* d_out, int out_size, void* d_ws, size_t ws_size,
                              hipStream_t stream) {
  (void)in_sizes; (void)n_in; (void)out_size;
  const float* z = (const float*)d_in[0];
  const float* u = (const float*)d_in[1];
  const float* Wi = (const float*)d_in[2];
  const float* bi = (const float*)d_in[3];
  const float* Wo = (const float*)d_in[4];
  const float* bo = (const float*)d_in[5];
  const float* E = (const float*)d_in[6];
  const float* csin = (const float*)d_in[7];
  float* outp = (float*)d_out;
  float* ws = (float*)d_ws;

  const size_t needNew = (size_t)ENDW * 4;
  if (ws_size >= needNew) {
    ushort* EB = (ushort*)(ws + EBW);
    ushort* ET = (ushort*)(ws + ETW);
    ushort* WOB = (ushort*)(ws + WOBW);
    ushort* ZDB = (ushort*)(ws + ZDBW);
    ushort* P = (ushort*)(ws + PW);

    hipMemsetAsync((void*)(ws + CSUMW), 0, (size_t)(2 * KCL + 64) * 4, stream);
    hipMemsetAsync((void*)(ws + ZD2W), 0, (size_t)NROWS * DDIM * 4, stream);

    e2c2_kernel<<<KCL / 64, 256, 0, stream>>>(E, ws + E2W, ws + C2W);
    etprep_kernel<<<512, 256, 0, stream>>>(E, ET, EB);
    cvtwob_kernel<<<128, 256, 0, stream>>>(Wo, WOB);
    inproj32_kernel<<<512, 256, 0, stream>>>(z, Wi, bi, ws + ZD2W);
    cvtwob_kernel<<<1024, 256, 0, stream>>>(ws + ZD2W, ZDB);  // zd -> bf16

    flashS2_kernel<<<512, 512, 0, stream>>>(ZDB, u, EB, ws + C2W, P,
                                            ws + LSPW, ws + CVW, (int*)(ws + CIW));
    rowfin_kernel<<<NROWS / 4, 256, 0, stream>>>(ws + LSPW, ws + CVW,
                                                 (const int*)(ws + CIW),
                                                 ws + ZD2W, E, ws + E2W, u,
                                                 ws + LINVW, ws + CNTW);
    // split-K partials scribbled into d_out (exactly OUT_SC floats), then
    // reduced into zq; outproj2 overwrites d_out afterwards. colsum fused here.
    pv2_kernel<<<512, 512, 0, stream>>>(P, ET, ws + LINVW, outp, ws + CSUMW);
    zqred_kernel<<<1024, 256, 0, stream>>>(outp, ws + LINVW, ws + ZD2W,
                                           ws + ZQ2W, ws + VQW);

    hipFuncSetAttribute(reinterpret_cast<const void*>(&outproj2_kernel),
                        hipFuncAttributeMaxDynamicSharedMemorySize, 65536);
    outproj2_kernel<<<2048, 256, 65536, stream>>>(ws + ZQ2W, WOB, bo, outp);
    finalize_kernel<<<1, 256, 0, stream>>>(ws + CSUMW, ws + CNTW, ws + VQW,
                                           csin, outp + OUT_SC, outp + OUT_SC + 4);
  } else {
    hipMemsetAsync((void*)(ws + CS_OFF), 0, (size_t)(2 * KCL + 1) * sizeof(float), stream);
    hipMemsetAsync((void*)(ws + ZD_OFF), 0, (size_t)NROWS * DDIM * 4, stream);
    e2_kernel<<<KCL / 64, 256, 0, stream>>>(E, ws + E2_OFF);
    inproj32_kernel<<<512, 256, 0, stream>>>(z, Wi, bi, ws + ZD_OFF);
    const int ldsB = (32 * 260 + 64 * 260 + 64 + 64 + 16) * 4;
    hipFuncSetAttribute(reinterpret_cast<const void*>(&flash_kernel<false>),
                        hipFuncAttributeMaxDynamicSharedMemorySize, ldsB);
    flash_kernel<false><<<NROWS / 32, 512, ldsB, stream>>>(
        ws + ZD_OFF, u, E, ws + E2_OFF, ws + ZQ_OFF, ws + CS_OFF, ws + CNT_OFF,
        ws + VQ_OFF, ws + LINV_OFF, (__half*)nullptr);
    outproj_kernel<<<(NROWS / 64) * 4, 256, 0, stream>>>(ws + ZQ_OFF, Wo, bo, outp);
    finalize_kernel<<<1, 256, 0, stream>>>(ws + CS_OFF, ws + CNT_OFF, ws + VQ_OFF,
                                           csin, outp + OUT_SC, outp + OUT_SC + 4);
  }
}